// Round 4
// baseline (1998.524 us; speedup 1.0000x reference)
//
#include <hip/hip_runtime.h>
#include <math.h>

#define N_NODES 50000
#define N_EDGES 800000
#define NB 256
#define AD 39
#define BD 10
#define H 128
#define HQ 64          // channels per half
#define HEADS 4
#define HD 32
#define LAYERS 3
#define TD 128

__device__ __forceinline__ float silu_f(float x) { return x / (1.f + __expf(-x)); }

// ---------------------------------------------------------------------------
// Generic node GEMM: out[N,OC] = act(A[N,K] @ W[K,OC](row-stride ldw) + bias
//                                     + bias2[gidx[n]])
// Block 256, tile NPB nodes x OC cols, 4x4 micro-tile.
// A staged transposed in LDS [K][NPB+4].
// ---------------------------------------------------------------------------
__global__ __launch_bounds__(256) void node_gemm(
    const float* __restrict__ A, const float* __restrict__ W,
    const float* __restrict__ bias, const float* __restrict__ bias2,
    const int* __restrict__ gidx, float* __restrict__ out,
    int Nrows, int K, int OC, int ldw, int NPB, int NCG, int act)
{
    extern __shared__ float A_lds[];  // [K][NPB+4]
    const int APAD = NPB + 4;
    const int tid = threadIdx.x;
    const int rowBase = blockIdx.x * NPB;

    for (int idx = tid; idx < NPB * K; idx += 256) {
        int node = idx / K;
        int k = idx - node * K;
        int n = rowBase + node;
        float v = (n < Nrows) ? A[(size_t)n * K + k] : 0.f;
        A_lds[k * APAD + node] = v;
    }
    __syncthreads();

    const int cg = tid % NCG;
    const int ng = tid / NCG;
    const int c0 = cg * 4, n0 = ng * 4;
    if (n0 >= NPB) return;

    float acc[16];
#pragma unroll
    for (int i = 0; i < 16; i++) acc[i] = 0.f;

    const bool vec4 = ((OC & 3) == 0);

    for (int k = 0; k < K; k++) {
        float4 a = *(const float4*)&A_lds[k * APAD + n0];
        float4 w;
        if (vec4) {
            w = *(const float4*)&W[(size_t)k * ldw + c0];
        } else {
            size_t base = (size_t)k * ldw + c0;
            w.x = (c0 + 0 < OC) ? W[base + 0] : 0.f;
            w.y = (c0 + 1 < OC) ? W[base + 1] : 0.f;
            w.z = (c0 + 2 < OC) ? W[base + 2] : 0.f;
            w.w = (c0 + 3 < OC) ? W[base + 3] : 0.f;
        }
        acc[0]  += a.x * w.x; acc[1]  += a.x * w.y; acc[2]  += a.x * w.z; acc[3]  += a.x * w.w;
        acc[4]  += a.y * w.x; acc[5]  += a.y * w.y; acc[6]  += a.y * w.z; acc[7]  += a.y * w.w;
        acc[8]  += a.z * w.x; acc[9]  += a.z * w.y; acc[10] += a.z * w.z; acc[11] += a.z * w.w;
        acc[12] += a.w * w.x; acc[13] += a.w * w.y; acc[14] += a.w * w.z; acc[15] += a.w * w.w;
    }

#pragma unroll
    for (int i = 0; i < 4; i++) {
        int n = rowBase + n0 + i;
        if (n >= Nrows) continue;
        int gb = bias2 ? gidx[n] : 0;
#pragma unroll
        for (int j = 0; j < 4; j++) {
            int c = c0 + j;
            if (c >= OC) continue;
            float v = acc[i * 4 + j];
            if (bias)  v += bias[c];
            if (bias2) v += bias2[(size_t)gb * H + c];
            if (act == 1) v = silu_f(v);
            out[(size_t)n * OC + c] = v;
        }
    }
}

static void launch_gemm(const float* A, const float* W, const float* bias,
                        const float* bias2, const int* gidx, float* out,
                        int Nrows, int K, int OC, int ldw, int act,
                        hipStream_t stream)
{
    int NCG = (OC + 3) / 4;
    int NPB = (256 / NCG) * 4;
    while ((size_t)K * (NPB + 4) * sizeof(float) > 64 * 1024) NPB >>= 1;
    size_t sh = (size_t)K * (NPB + 4) * sizeof(float);
    int blocks = (Nrows + NPB - 1) / NPB;
    node_gemm<<<blocks, 256, sh, stream>>>(A, W, bias, bias2, gidx, out,
                                           Nrows, K, OC, ldw, NPB, NCG, act);
}

// ---------------------------------------------------------------------------
// Fold edge path: mc[l][j][hh] coefficients, mc[l][40+hh] constants.
// ---------------------------------------------------------------------------
__global__ __launch_bounds__(256) void precompute_small(
    const float* __restrict__ edge_W, const float* __restrict__ att_edge,
    const float* __restrict__ bond_W, const float* __restrict__ bond_b,
    float* __restrict__ mc)
{
    __shared__ float bl[LAYERS][H][4];
    int tid = threadIdx.x;
    for (int task = tid; task < LAYERS * H; task += 256) {
        int l = task / H, k = task % H;
#pragma unroll
        for (int hh = 0; hh < 4; hh++) {
            float s = 0.f;
            for (int d = 0; d < HD; d++)
                s += edge_W[(size_t)l * H * H + k * H + hh * HD + d] *
                     att_edge[l * H + hh * HD + d];
            bl[l][k][hh] = s;
        }
    }
    __syncthreads();
    if (tid < LAYERS * BD * 4) {
        int l = tid / (BD * 4), r = tid % (BD * 4), j = r / 4, hh = r % 4;
        float s = 0.f;
        for (int k = 0; k < H; k++) s += bond_W[j * H + k] * bl[l][k][hh];
        mc[l * 44 + j * 4 + hh] = s;
    }
    if (tid >= 128 && tid < 128 + LAYERS * 4) {
        int r = tid - 128, l = r / 4, hh = r % 4;
        float s = 0.f;
        for (int k = 0; k < H; k++) s += bond_b[k] * bl[l][k][hh];
        mc[l * 44 + 40 + hh] = s;
    }
}

// ---------------------------------------------------------------------------
__global__ __launch_bounds__(128) void time_embed(
    const int* __restrict__ t,
    const float* __restrict__ W1, const float* __restrict__ b1,
    const float* __restrict__ W2, const float* __restrict__ b2,
    float* __restrict__ t_emb)
{
    int g = blockIdx.x, c = threadIdx.x;
    float tf = (float)t[g];
    __shared__ float emb[TD], z[H];
    int k = c & 63;
    float f = __expf(-9.210340371976184f * (float)k / 63.0f);
    float e = tf * f;
    emb[c] = (c < 64) ? sinf(e) : cosf(e);
    __syncthreads();
    float a1 = b1[c];
    for (int kk = 0; kk < TD; kk++) a1 += emb[kk] * W1[kk * H + c];
    z[c] = silu_f(a1);
    __syncthreads();
    float a2 = b2[c];
    for (int kk = 0; kk < H; kk++) a2 += z[kk] * W2[kk * H + c];
    t_emb[g * H + c] = a2;
}

// ---------------------------------------------------------------------------
// CSR build (tables live in d_out scratch)
// ---------------------------------------------------------------------------
__global__ __launch_bounds__(256) void hist_dst(const int* __restrict__ edge_index,
                                                int* __restrict__ deg)
{
    int e = blockIdx.x * 256 + threadIdx.x;
    if (e < N_EDGES) atomicAdd(&deg[edge_index[N_EDGES + e]], 1);
}

__global__ __launch_bounds__(256) void hist_batch(const int* __restrict__ batch,
                                                  int* __restrict__ gcnt)
{
    int n = blockIdx.x * 256 + threadIdx.x;
    if (n < N_NODES) atomicAdd(&gcnt[batch[n]], 1);
}

__global__ __launch_bounds__(1024) void scan_big(const int* __restrict__ cnt,
                                                 int* __restrict__ ptr, int n)
{
    int t = threadIdx.x;
    int per = (n + 1023) / 1024;
    int s0 = t * per, s1 = min(n, s0 + per);
    if (s0 > n) s0 = n;
    int sum = 0;
    for (int i = s0; i < s1; i++) sum += cnt[i];
    __shared__ int ps[1024];
    ps[t] = sum;
    __syncthreads();
    for (int off = 1; off < 1024; off <<= 1) {
        int v = (t >= off) ? ps[t - off] : 0;
        __syncthreads();
        ps[t] += v;
        __syncthreads();
    }
    int run = (t == 0) ? 0 : ps[t - 1];
    for (int i = s0; i < s1; i++) { ptr[i] = run; run += cnt[i]; }
    if (t == 1023) ptr[n] = ps[1023];
}

__global__ __launch_bounds__(256) void scatter_edges(const int* __restrict__ edge_index,
                                                     const int* __restrict__ ptr,
                                                     int* __restrict__ cursor,
                                                     int* __restrict__ csr_edge)
{
    int e = blockIdx.x * 256 + threadIdx.x;
    if (e >= N_EDGES) return;
    int d = edge_index[N_EDGES + e];
    int pos = atomicAdd(&cursor[d], 1);
    csr_edge[ptr[d] + pos] = e;
}

// ---------------------------------------------------------------------------
// Attention scores for one half (2 heads): 4 nodes per 256-thr block.
// ---------------------------------------------------------------------------
__global__ __launch_bounds__(256) void attn_scores_h(
    const float* __restrict__ xh_h, const float* __restrict__ a_src,
    const float* __restrict__ a_dst, int hh0,
    float* __restrict__ sS, float* __restrict__ sD)
{
    int tid = threadIdx.x;
    int n = blockIdx.x * 4 + (tid >> 6);
    int c = tid & 63;
    float v = xh_h[(size_t)n * HQ + c];
    int hh = c >> 5;
    float as = v * a_src[(hh0 + hh) * 32 + (c & 31)];
    float ad = v * a_dst[(hh0 + hh) * 32 + (c & 31)];
#pragma unroll
    for (int off = 16; off >= 1; off >>= 1) {
        as += __shfl_xor(as, off, 32);
        ad += __shfl_xor(ad, off, 32);
    }
    if ((c & 31) == 0) {
        sS[n * 2 + hh] = as;
        sD[n * 2 + hh] = ad;
    }
}

// ---------------------------------------------------------------------------
// Per-edge scores for one half: alpha[e][2]
// ---------------------------------------------------------------------------
__global__ __launch_bounds__(256) void edge_scores_h(
    const float* __restrict__ edge_attr, const int* __restrict__ edge_index,
    const float* __restrict__ mc_l, int hh0,
    const float* __restrict__ sS, const float* __restrict__ sD,
    float* __restrict__ alpha)
{
    __shared__ float Ml[BD * 2], cl2[2];
    int tid = threadIdx.x;
    if (tid < BD * 2) Ml[tid] = mc_l[(tid >> 1) * 4 + hh0 + (tid & 1)];
    if (tid >= 32 && tid < 34) cl2[tid - 32] = mc_l[40 + hh0 + (tid - 32)];
    __syncthreads();
    int e = blockIdx.x * 256 + tid;
    if (e >= N_EDGES) return;
    float se0 = cl2[0], se1 = cl2[1];
#pragma unroll
    for (int j = 0; j < BD; j++) {
        float x = edge_attr[(size_t)e * BD + j];
        se0 += x * Ml[j * 2 + 0];
        se1 += x * Ml[j * 2 + 1];
    }
    int s = edge_index[e];
    int d = edge_index[N_EDGES + e];
    float2 ss = *(const float2*)&sS[s * 2];
    float2 sd = *(const float2*)&sD[d * 2];
    float2 o;
    float a;
    a = ss.x + sd.x + se0; o.x = (a >= 0.f) ? a : 0.2f * a;
    a = ss.y + sd.y + se1; o.y = (a >= 0.f) ? a : 0.2f * a;
    *(float2*)&alpha[(size_t)e * 2] = o;
}

// ---------------------------------------------------------------------------
// GAT aggregation for one half: one wave per dst node, online softmax.
// lane = channel (64 ch), local head = lane>>5.
// ---------------------------------------------------------------------------
__global__ __launch_bounds__(256) void gat_agg_h(
    const float* __restrict__ xh_h, const float* __restrict__ alpha,
    const int* __restrict__ csr_ptr, const int* __restrict__ csr_edge,
    const int* __restrict__ src_idx, const float* __restrict__ conv_b_off,
    float* __restrict__ agg)
{
    int n = (blockIdx.x * 256 + threadIdx.x) >> 6;
    if (n >= N_NODES) return;
    int lane = threadIdx.x & 63;
    int hd = lane >> 5;
    int start = csr_ptr[n], end = csr_ptr[n + 1];

    float m_run = -1e30f, d_run = 0.f, acc = 0.f;

    for (int base = start; base < end; base += 64) {
        int cnt = min(64, end - base);
        int e_l = 0, s_l = 0;
        if (lane < cnt) {
            e_l = csr_edge[base + lane];
            s_l = src_idx[e_l];
        }
        float a_t[2];
        float m_blk = -1e30f;
#pragma unroll
        for (int tt = 0; tt < 2; tt++) {
            int i = (lane & 31) + tt * 32;
            float a = -1e30f;
            if (i < cnt) {
                int e = __shfl(e_l, i);
                a = alpha[(size_t)e * 2 + hd];
            }
            a_t[tt] = a;
            m_blk = fmaxf(m_blk, a);
        }
#pragma unroll
        for (int off = 16; off >= 1; off >>= 1)
            m_blk = fmaxf(m_blk, __shfl_xor(m_blk, off, 32));
        float m_new = fmaxf(m_run, m_blk);
        float rescale = __expf(m_run - m_new);
        float dsum = __expf(a_t[0] - m_new) + __expf(a_t[1] - m_new);
#pragma unroll
        for (int off = 16; off >= 1; off >>= 1)
            dsum += __shfl_xor(dsum, off, 32);
        d_run = d_run * rescale + dsum;
        acc *= rescale;
        for (int i = 0; i < cnt; i++) {
            int e = __shfl(e_l, i);
            int s = __shfl(s_l, i);
            float a = alpha[(size_t)e * 2 + hd];
            float w = __expf(a - m_new);
            acc += xh_h[(size_t)s * HQ + lane] * w;
        }
        m_run = m_new;
    }
    float inv = 1.f / (d_run + 1e-16f);
    agg[(size_t)n * HQ + lane] = acc * inv + conv_b_off[lane];
}

// ---------------------------------------------------------------------------
// BatchNorm (per half, 64 channels): two-stage deterministic reduction
// ---------------------------------------------------------------------------
__global__ __launch_bounds__(64) void bn_partial_h(const float* __restrict__ agg,
                                                   float* __restrict__ part)
{
    int b = blockIdx.x;   // 256 blocks
    int c = threadIdx.x;  // 64
    int per = (N_NODES + 255) / 256;
    int s = b * per, e = min(N_NODES, s + per);
    float sum = 0.f, sq = 0.f;
    for (int n = s; n < e; n++) {
        float v = agg[(size_t)n * HQ + c];
        sum += v; sq += v * v;
    }
    part[b * HQ + c] = sum;
    part[256 * HQ + b * HQ + c] = sq;
}

__global__ __launch_bounds__(64) void bn_finish_h(const float* __restrict__ part,
                                                  const float* __restrict__ gamma,
                                                  const float* __restrict__ beta,
                                                  float* __restrict__ scale,
                                                  float* __restrict__ shift)
{
    int c = threadIdx.x;
    double s = 0.0, q = 0.0;
    for (int b = 0; b < 256; b++) {
        s += (double)part[b * HQ + c];
        q += (double)part[256 * HQ + b * HQ + c];
    }
    float mu = (float)(s / N_NODES);
    float var = (float)(q / N_NODES) - mu * mu;
    float rstd = rsqrtf(var + 1e-5f);
    float sc = gamma[c] * rstd;
    scale[c] = sc;
    shift[c] = beta[c] - mu * sc;
}

__global__ __launch_bounds__(256) void bn_apply_h(const float* __restrict__ agg,
                                                  const float* __restrict__ scale,
                                                  const float* __restrict__ shift,
                                                  float* __restrict__ h, int coff)
{
    int i = blockIdx.x * 256 + threadIdx.x;  // over N*HQ/4
    if (i >= N_NODES * HQ / 4) return;
    int n = i >> 4;
    int c0 = (i & 15) * 4;
    float4 v = *(const float4*)&agg[(size_t)n * HQ + c0];
    float4 sc = *(const float4*)&scale[c0];
    float4 sh = *(const float4*)&shift[c0];
    float* hp = &h[(size_t)n * H + coff + c0];
    float4 hv = *(const float4*)hp;
    float4 o;
    o.x = fmaxf(v.x * sc.x + sh.x, 0.f) + hv.x;
    o.y = fmaxf(v.y * sc.y + sh.y, 0.f) + hv.y;
    o.z = fmaxf(v.z * sc.z + sh.z, 0.f) + hv.z;
    o.w = fmaxf(v.w * sc.w + sh.w, 0.f) + hv.w;
    *(float4*)hp = o;
}

// ---------------------------------------------------------------------------
// Graph head: mean pool + pool MLP + t_emb add + fold tg through np_W1[128:]
// ---------------------------------------------------------------------------
__global__ __launch_bounds__(128) void graph_head(
    const float* __restrict__ nf, const int* __restrict__ gptr,
    const float* __restrict__ t_emb,
    const float* __restrict__ pW1, const float* __restrict__ pb1,
    const float* __restrict__ pW2, const float* __restrict__ pb2,
    const float* __restrict__ npW1, const float* __restrict__ npb1,
    float* __restrict__ tgW)
{
    int g = blockIdx.x, c = threadIdx.x;
    int s = gptr[g], e = gptr[g + 1];
    float sum = 0.f;
    for (int n = s; n < e; n++) sum += nf[(size_t)n * H + c];
    float cf = (e - s > 0) ? (float)(e - s) : 1.f;
    __shared__ float row[H], z[H];
    row[c] = sum / cf;
    __syncthreads();
    float a1 = pb1[c];
    for (int k = 0; k < H; k++) a1 += row[k] * pW1[k * H + c];
    z[c] = silu_f(a1);
    __syncthreads();
    float a2 = pb2[c];
    for (int k = 0; k < H; k++) a2 += z[k] * pW2[k * H + c];
    float tg = a2 + t_emb[g * H + c];
    __syncthreads();
    row[c] = tg;
    __syncthreads();
    float a3 = npb1[c];
    for (int k = 0; k < H; k++) a3 += row[k] * npW1[(size_t)(128 + k) * H + c];
    tgW[g * H + c] = a3;
}

// ---------------------------------------------------------------------------
extern "C" void kernel_launch(void* const* d_in, const int* in_sizes, int n_in,
                              void* d_out, int out_size, void* d_ws, size_t ws_size,
                              hipStream_t stream)
{
    const float* x          = (const float*)d_in[0];
    const int*   edge_index = (const int*)d_in[1];
    const float* edge_attr  = (const float*)d_in[2];
    const int*   batch      = (const int*)d_in[3];
    const int*   t          = (const int*)d_in[4];
    const float* atom_W     = (const float*)d_in[5];
    const float* atom_b     = (const float*)d_in[6];
    const float* bond_W     = (const float*)d_in[7];
    const float* bond_b     = (const float*)d_in[8];
    const float* lin_W      = (const float*)d_in[9];
    const float* edge_W     = (const float*)d_in[10];
    const float* att_src    = (const float*)d_in[11];
    const float* att_dst    = (const float*)d_in[12];
    const float* att_edge   = (const float*)d_in[13];
    const float* conv_b     = (const float*)d_in[14];
    const float* bn_gamma   = (const float*)d_in[15];
    const float* bn_beta    = (const float*)d_in[16];
    const float* out_W      = (const float*)d_in[17];
    const float* out_b      = (const float*)d_in[18];
    const float* time_W1    = (const float*)d_in[19];
    const float* time_b1    = (const float*)d_in[20];
    const float* time_W2    = (const float*)d_in[21];
    const float* time_b2    = (const float*)d_in[22];
    const float* pool_W1    = (const float*)d_in[23];
    const float* pool_b1    = (const float*)d_in[24];
    const float* pool_W2    = (const float*)d_in[25];
    const float* pool_b2    = (const float*)d_in[26];
    const float* np_W1      = (const float*)d_in[27];
    const float* np_b1      = (const float*)d_in[28];
    const float* np_W2      = (const float*)d_in[29];
    const float* np_b2      = (const float*)d_in[30];
    const float* np_W3      = (const float*)d_in[31];
    const float* np_b3      = (const float*)d_in[32];

    // ---------------- workspace layout (floats), total 71.6 MB ----------------
    const size_t OFF_H     = 0;                      // [N*H]   6,400,000
    const size_t OFF_XH    = 6400000;                // [N*H]   (2 halves [N,64])
    const size_t OFF_AGG   = 12800000;               // [N*HQ]  3,200,000
    const size_t OFF_ALPHA = 16000000;               // [E*2]   1,600,000
    const size_t OFF_SS    = 17600000;               // [N*2]
    const size_t OFF_SD    = 17700000;               // [N*2]
    const size_t OFF_TEMB  = 17800000;               // [NB*H]  32768
    const size_t OFF_TGW   = 17832768;               // [NB*H]  32768
    const size_t OFF_MC    = 17865536;               // 256
    const size_t OFF_BNSC  = 17865792;               // 128
    const size_t OFF_BNSH  = 17865920;               // 128
    const size_t OFF_PART  = 17866048;               // 256*HQ*2 = 32768
    const size_t REQ_FLOATS = 17898816;
    const size_t REQ_BYTES  = REQ_FLOATS * 4;        // 71,595,264

    if (ws_size < REQ_BYTES) {
        // signal "workspace too small" via deterministic zero output
        hipMemsetAsync(d_out, 0, (size_t)out_size * sizeof(float), stream);
        return;
    }

    float* fws   = (float*)d_ws;
    float* h     = fws + OFF_H;
    float* xh    = fws + OFF_XH;
    float* agg   = fws + OFF_AGG;
    float* alpha = fws + OFF_ALPHA;
    float* sS    = fws + OFF_SS;
    float* sD    = fws + OFF_SD;
    float* t_emb = fws + OFF_TEMB;
    float* tgW   = fws + OFF_TGW;
    float* mc    = fws + OFF_MC;
    float* bnsc  = fws + OFF_BNSC;
    float* bnsh  = fws + OFF_BNSH;
    float* part  = fws + OFF_PART;

    // CSR integer tables live in d_out scratch (1.95M floats = 7.8 MB >> 3.6 MB
    // needed). All CSR consumers finish before the final GEMM overwrites d_out.
    int* ib       = (int*)d_out;
    int* csr_ptr  = ib;                  // 50048
    int* csr_edge = ib + 50048;          // 800000
    int* deg      = ib + 850048;         // 50048 (also scatter cursor)
    int* gcnt     = ib + 900096;         // 256
    int* gptr     = ib + 900352;         // 257   (end: 900609 ints)

    hipMemsetAsync(deg, 0, N_NODES * sizeof(int), stream);
    hipMemsetAsync(gcnt, 0, NB * sizeof(int), stream);

    precompute_small<<<1, 256, 0, stream>>>(edge_W, att_edge, bond_W, bond_b, mc);
    time_embed<<<NB, 128, 0, stream>>>(t, time_W1, time_b1, time_W2, time_b2, t_emb);

    hist_dst<<<(N_EDGES + 255) / 256, 256, 0, stream>>>(edge_index, deg);
    hist_batch<<<(N_NODES + 255) / 256, 256, 0, stream>>>(batch, gcnt);
    scan_big<<<1, 1024, 0, stream>>>(deg, csr_ptr, N_NODES);
    scan_big<<<1, 1024, 0, stream>>>(gcnt, gptr, NB);
    hipMemsetAsync(deg, 0, N_NODES * sizeof(int), stream);
    scatter_edges<<<(N_EDGES + 255) / 256, 256, 0, stream>>>(edge_index, csr_ptr, deg, csr_edge);

    // h = x @ atom_W + atom_b
    launch_gemm(x, atom_W, atom_b, nullptr, nullptr, h, N_NODES, AD, H, H, 0, stream);

    for (int l = 0; l < LAYERS; l++) {
        // both xh halves from the layer-input h (before any residual update)
        for (int half = 0; half < 2; half++) {
            launch_gemm(h, lin_W + (size_t)l * H * H + half * HQ, nullptr, nullptr,
                        nullptr, xh + (size_t)half * N_NODES * HQ,
                        N_NODES, H, HQ, H, 0, stream);
        }
        for (int half = 0; half < 2; half++) {
            const float* xh_h = xh + (size_t)half * N_NODES * HQ;
            int hh0 = half * 2;
            int coff = half * HQ;
            attn_scores_h<<<N_NODES / 4, 256, 0, stream>>>(
                xh_h, att_src + l * H, att_dst + l * H, hh0, sS, sD);
            edge_scores_h<<<(N_EDGES + 255) / 256, 256, 0, stream>>>(
                edge_attr, edge_index, mc + l * 44, hh0, sS, sD, alpha);
            gat_agg_h<<<N_NODES / 4, 256, 0, stream>>>(
                xh_h, alpha, csr_ptr, csr_edge, edge_index,
                conv_b + l * H + coff, agg);
            bn_partial_h<<<256, 64, 0, stream>>>(agg, part);
            bn_finish_h<<<1, 64, 0, stream>>>(part, bn_gamma + l * H + coff,
                                              bn_beta + l * H + coff, bnsc, bnsh);
            bn_apply_h<<<(N_NODES * HQ / 4 + 255) / 256, 256, 0, stream>>>(
                agg, bnsc, bnsh, h, coff);
        }
    }

    // node_features = h @ out_W + out_b  -> xh (reused as [N,128])
    launch_gemm(h, out_W, out_b, nullptr, nullptr, xh, N_NODES, H, H, H, 0, stream);

    graph_head<<<NB, 128, 0, stream>>>(xh, gptr, t_emb, pool_W1, pool_b1,
                                       pool_W2, pool_b2, np_W1, np_b1, tgW);

    // z1 = silu(nf @ np_W1[0:128] + tgW[batch])  -> h (dead)
    launch_gemm(xh, np_W1, nullptr, tgW, batch, h, N_NODES, H, H, H, 1, stream);
    // z2 = silu(z1 @ np_W2 + np_b2) -> xh (dead)
    launch_gemm(h, np_W2, np_b2, nullptr, nullptr, xh, N_NODES, H, H, H, 1, stream);
    // out = z2 @ np_W3 + np_b3 -> d_out [N, 39]  (overwrites CSR scratch, now dead)
    launch_gemm(xh, np_W3, np_b3, nullptr, nullptr, (float*)d_out, N_NODES, H, AD, AD, 0, stream);
}

// Round 5
// 1503.229 us; speedup vs baseline: 1.3295x; 1.3295x over previous
//
#include <hip/hip_runtime.h>
#include <math.h>

#define N_NODES 50000
#define N_EDGES 800000
#define NB 256
#define AD 39
#define BD 10
#define H 128
#define HQ 64
#define HEADS 4
#define HD 32
#define LAYERS 3
#define TD 128

__device__ __forceinline__ float silu_f(float x) { return x / (1.f + __expf(-x)); }

// ---------------------------------------------------------------------------
// Specialized GEMM: out[N,128] = act(A[N,KT] @ W[KT,128](ldw) + bias
//                                    + bias2[gidx[n]])
// 256 thr; 64-row tile; thread = 8 rows x 4 cols; k-loop unrolled x4.
// A staged transposed in LDS [KT][68]; k-loop LDS reads are uniform per
// half-wave (broadcast, conflict-free).
// ---------------------------------------------------------------------------
__device__ __forceinline__ void fma_rank1(float acc[8][4], float4 aL, float4 aH, float4 w)
{
    float ar[8] = {aL.x, aL.y, aL.z, aL.w, aH.x, aH.y, aH.z, aH.w};
    float wr[4] = {w.x, w.y, w.z, w.w};
#pragma unroll
    for (int r = 0; r < 8; r++)
#pragma unroll
        for (int j = 0; j < 4; j++) acc[r][j] += ar[r] * wr[j];
}

template<int KT>
__global__ __launch_bounds__(256) void gemm128(
    const float* __restrict__ A, const float* __restrict__ W,
    const float* __restrict__ bias, const float* __restrict__ bias2,
    const int* __restrict__ gidx, float* __restrict__ out,
    int Nrows, int ldw, int act)
{
    __shared__ float As[KT * 68];
    const int tid = threadIdx.x;
    const int rowBase = blockIdx.x * 64;

    for (int idx = tid; idx < 64 * KT; idx += 256) {
        int row = idx / KT;
        int k = idx - row * KT;
        int n = rowBase + row;
        As[k * 68 + row] = (n < Nrows) ? A[(size_t)n * KT + k] : 0.f;
    }
    __syncthreads();

    const int c0 = (tid & 31) * 4;
    const int n0 = (tid >> 5) * 8;

    float acc[8][4];
#pragma unroll
    for (int r = 0; r < 8; r++)
#pragma unroll
        for (int j = 0; j < 4; j++) acc[r][j] = 0.f;

    const float* wp = W + c0;
    int k = 0;
    for (; k + 4 <= KT; k += 4) {
        float4 w0 = *(const float4*)&wp[(size_t)(k + 0) * ldw];
        float4 w1 = *(const float4*)&wp[(size_t)(k + 1) * ldw];
        float4 w2 = *(const float4*)&wp[(size_t)(k + 2) * ldw];
        float4 w3 = *(const float4*)&wp[(size_t)(k + 3) * ldw];
        float4 aL0 = *(const float4*)&As[(k + 0) * 68 + n0];
        float4 aH0 = *(const float4*)&As[(k + 0) * 68 + n0 + 4];
        float4 aL1 = *(const float4*)&As[(k + 1) * 68 + n0];
        float4 aH1 = *(const float4*)&As[(k + 1) * 68 + n0 + 4];
        float4 aL2 = *(const float4*)&As[(k + 2) * 68 + n0];
        float4 aH2 = *(const float4*)&As[(k + 2) * 68 + n0 + 4];
        float4 aL3 = *(const float4*)&As[(k + 3) * 68 + n0];
        float4 aH3 = *(const float4*)&As[(k + 3) * 68 + n0 + 4];
        fma_rank1(acc, aL0, aH0, w0);
        fma_rank1(acc, aL1, aH1, w1);
        fma_rank1(acc, aL2, aH2, w2);
        fma_rank1(acc, aL3, aH3, w3);
    }
    for (; k < KT; ++k) {
        float4 w0 = *(const float4*)&wp[(size_t)k * ldw];
        float4 aL = *(const float4*)&As[k * 68 + n0];
        float4 aH = *(const float4*)&As[k * 68 + n0 + 4];
        fma_rank1(acc, aL, aH, w0);
    }

    float4 bv = make_float4(0.f, 0.f, 0.f, 0.f);
    if (bias) bv = *(const float4*)&bias[c0];
#pragma unroll
    for (int r = 0; r < 8; r++) {
        int n = rowBase + n0 + r;
        if (n >= Nrows) break;
        float4 o;
        o.x = acc[r][0] + bv.x;
        o.y = acc[r][1] + bv.y;
        o.z = acc[r][2] + bv.z;
        o.w = acc[r][3] + bv.w;
        if (bias2) {
            float4 b2 = *(const float4*)&bias2[(size_t)gidx[n] * H + c0];
            o.x += b2.x; o.y += b2.y; o.z += b2.z; o.w += b2.w;
        }
        if (act) {
            o.x = silu_f(o.x); o.y = silu_f(o.y);
            o.z = silu_f(o.z); o.w = silu_f(o.w);
        }
        *(float4*)&out[(size_t)n * H + c0] = o;
    }
}

// ---------------------------------------------------------------------------
// Generic node GEMM (only np_W3: K=128, OC=39 now)
// ---------------------------------------------------------------------------
__global__ __launch_bounds__(256) void node_gemm(
    const float* __restrict__ A, const float* __restrict__ W,
    const float* __restrict__ bias, float* __restrict__ out,
    int Nrows, int K, int OC, int ldw, int NPB, int NCG)
{
    extern __shared__ float A_lds[];
    const int APAD = NPB + 4;
    const int tid = threadIdx.x;
    const int rowBase = blockIdx.x * NPB;

    for (int idx = tid; idx < NPB * K; idx += 256) {
        int node = idx / K;
        int k = idx - node * K;
        int n = rowBase + node;
        float v = (n < Nrows) ? A[(size_t)n * K + k] : 0.f;
        A_lds[k * APAD + node] = v;
    }
    __syncthreads();

    const int cg = tid % NCG;
    const int ng = tid / NCG;
    const int c0 = cg * 4, n0 = ng * 4;
    if (n0 >= NPB) return;

    float acc[16];
#pragma unroll
    for (int i = 0; i < 16; i++) acc[i] = 0.f;

    for (int k = 0; k < K; k++) {
        float4 a = *(const float4*)&A_lds[k * APAD + n0];
        size_t base = (size_t)k * ldw + c0;
        float4 w;
        w.x = (c0 + 0 < OC) ? W[base + 0] : 0.f;
        w.y = (c0 + 1 < OC) ? W[base + 1] : 0.f;
        w.z = (c0 + 2 < OC) ? W[base + 2] : 0.f;
        w.w = (c0 + 3 < OC) ? W[base + 3] : 0.f;
        acc[0]  += a.x * w.x; acc[1]  += a.x * w.y; acc[2]  += a.x * w.z; acc[3]  += a.x * w.w;
        acc[4]  += a.y * w.x; acc[5]  += a.y * w.y; acc[6]  += a.y * w.z; acc[7]  += a.y * w.w;
        acc[8]  += a.z * w.x; acc[9]  += a.z * w.y; acc[10] += a.z * w.z; acc[11] += a.z * w.w;
        acc[12] += a.w * w.x; acc[13] += a.w * w.y; acc[14] += a.w * w.z; acc[15] += a.w * w.w;
    }

#pragma unroll
    for (int i = 0; i < 4; i++) {
        int n = rowBase + n0 + i;
        if (n >= Nrows) continue;
#pragma unroll
        for (int j = 0; j < 4; j++) {
            int c = c0 + j;
            if (c >= OC) continue;
            float v = acc[i * 4 + j];
            if (bias) v += bias[c];
            out[(size_t)n * OC + c] = v;
        }
    }
}

// ---------------------------------------------------------------------------
// Fold edge path coefficients
// ---------------------------------------------------------------------------
__global__ __launch_bounds__(256) void precompute_small(
    const float* __restrict__ edge_W, const float* __restrict__ att_edge,
    const float* __restrict__ bond_W, const float* __restrict__ bond_b,
    float* __restrict__ mc)
{
    __shared__ float bl[LAYERS][H][4];
    int tid = threadIdx.x;
    for (int task = tid; task < LAYERS * H; task += 256) {
        int l = task / H, k = task % H;
#pragma unroll
        for (int hh = 0; hh < 4; hh++) {
            float s = 0.f;
            for (int d = 0; d < HD; d++)
                s += edge_W[(size_t)l * H * H + k * H + hh * HD + d] *
                     att_edge[l * H + hh * HD + d];
            bl[l][k][hh] = s;
        }
    }
    __syncthreads();
    if (tid < LAYERS * BD * 4) {
        int l = tid / (BD * 4), r = tid % (BD * 4), j = r / 4, hh = r % 4;
        float s = 0.f;
        for (int k = 0; k < H; k++) s += bond_W[j * H + k] * bl[l][k][hh];
        mc[l * 44 + j * 4 + hh] = s;
    }
    if (tid >= 128 && tid < 128 + LAYERS * 4) {
        int r = tid - 128, l = r / 4, hh = r % 4;
        float s = 0.f;
        for (int k = 0; k < H; k++) s += bond_b[k] * bl[l][k][hh];
        mc[l * 44 + 40 + hh] = s;
    }
}

// ---------------------------------------------------------------------------
__global__ __launch_bounds__(128) void time_embed(
    const int* __restrict__ t,
    const float* __restrict__ W1, const float* __restrict__ b1,
    const float* __restrict__ W2, const float* __restrict__ b2,
    float* __restrict__ t_emb)
{
    int g = blockIdx.x, c = threadIdx.x;
    float tf = (float)t[g];
    __shared__ float emb[TD], z[H];
    int k = c & 63;
    float f = __expf(-9.210340371976184f * (float)k / 63.0f);
    float e = tf * f;
    emb[c] = (c < 64) ? sinf(e) : cosf(e);
    __syncthreads();
    float a1 = b1[c];
    for (int kk = 0; kk < TD; kk++) a1 += emb[kk] * W1[kk * H + c];
    z[c] = silu_f(a1);
    __syncthreads();
    float a2 = b2[c];
    for (int kk = 0; kk < H; kk++) a2 += z[kk] * W2[kk * H + c];
    t_emb[g * H + c] = a2;
}

// ---------------------------------------------------------------------------
// CSR build
// ---------------------------------------------------------------------------
__global__ __launch_bounds__(256) void hist_dst(const int* __restrict__ edge_index,
                                                int* __restrict__ deg)
{
    int e = blockIdx.x * 256 + threadIdx.x;
    if (e < N_EDGES) atomicAdd(&deg[edge_index[N_EDGES + e]], 1);
}

__global__ __launch_bounds__(256) void hist_batch(const int* __restrict__ batch,
                                                  int* __restrict__ gcnt)
{
    int n = blockIdx.x * 256 + threadIdx.x;
    if (n < N_NODES) atomicAdd(&gcnt[batch[n]], 1);
}

__global__ __launch_bounds__(1024) void scan_big(const int* __restrict__ cnt,
                                                 int* __restrict__ ptr, int n)
{
    int t = threadIdx.x;
    int per = (n + 1023) / 1024;
    int s0 = t * per, s1 = min(n, s0 + per);
    if (s0 > n) s0 = n;
    int sum = 0;
    for (int i = s0; i < s1; i++) sum += cnt[i];
    __shared__ int ps[1024];
    ps[t] = sum;
    __syncthreads();
    for (int off = 1; off < 1024; off <<= 1) {
        int v = (t >= off) ? ps[t - off] : 0;
        __syncthreads();
        ps[t] += v;
        __syncthreads();
    }
    int run = (t == 0) ? 0 : ps[t - 1];
    for (int i = s0; i < s1; i++) { ptr[i] = run; run += cnt[i]; }
    if (t == 1023) ptr[n] = ps[1023];
}

__global__ __launch_bounds__(256) void scatter_edges(const int* __restrict__ edge_index,
                                                     const int* __restrict__ ptr,
                                                     int* __restrict__ cursor,
                                                     int* __restrict__ csr_edge)
{
    int e = blockIdx.x * 256 + threadIdx.x;
    if (e >= N_EDGES) return;
    int d = edge_index[N_EDGES + e];
    int pos = atomicAdd(&cursor[d], 1);
    csr_edge[ptr[d] + pos] = e;
}

// ---------------------------------------------------------------------------
// Attention scores, all 4 heads: 2 nodes per 256-thr block.
// ---------------------------------------------------------------------------
__global__ __launch_bounds__(256) void attn_scores(
    const float* __restrict__ xh, const float* __restrict__ att_src,
    const float* __restrict__ att_dst, float* __restrict__ s_src,
    float* __restrict__ s_dst)
{
    int tid = threadIdx.x;
    int n = blockIdx.x * 2 + (tid >> 7);
    int c = tid & 127;
    float v = xh[(size_t)n * H + c];
    float as = v * att_src[c];
    float ad = v * att_dst[c];
#pragma unroll
    for (int off = 16; off >= 1; off >>= 1) {
        as += __shfl_xor(as, off, 32);
        ad += __shfl_xor(ad, off, 32);
    }
    if ((c & 31) == 0) {
        s_src[n * 4 + (c >> 5)] = as;
        s_dst[n * 4 + (c >> 5)] = ad;
    }
}

// ---------------------------------------------------------------------------
// Per-edge scores for one half (heads hh0, hh0+1): alpha[e][2]
// ---------------------------------------------------------------------------
__global__ __launch_bounds__(256) void edge_scores_h(
    const float* __restrict__ edge_attr, const int* __restrict__ edge_index,
    const float* __restrict__ mc_l, int hh0,
    const float* __restrict__ sS, const float* __restrict__ sD,
    float* __restrict__ alpha)
{
    __shared__ float Ml[BD * 2], cl2[2];
    int tid = threadIdx.x;
    if (tid < BD * 2) Ml[tid] = mc_l[(tid >> 1) * 4 + hh0 + (tid & 1)];
    if (tid >= 32 && tid < 34) cl2[tid - 32] = mc_l[40 + hh0 + (tid - 32)];
    __syncthreads();
    int e = blockIdx.x * 256 + tid;
    if (e >= N_EDGES) return;
    float se0 = cl2[0], se1 = cl2[1];
#pragma unroll
    for (int j = 0; j < BD; j++) {
        float x = edge_attr[(size_t)e * BD + j];
        se0 += x * Ml[j * 2 + 0];
        se1 += x * Ml[j * 2 + 1];
    }
    int s = edge_index[e];
    int d = edge_index[N_EDGES + e];
    float ss0 = sS[s * 4 + hh0], ss1 = sS[s * 4 + hh0 + 1];
    float sd0 = sD[d * 4 + hh0], sd1 = sD[d * 4 + hh0 + 1];
    float2 o;
    float a;
    a = ss0 + sd0 + se0; o.x = (a >= 0.f) ? a : 0.2f * a;
    a = ss1 + sd1 + se1; o.y = (a >= 0.f) ? a : 0.2f * a;
    *(float2*)&alpha[(size_t)e * 2] = o;
}

// ---------------------------------------------------------------------------
// GAT aggregation for one half: one wave per dst node, online softmax.
// xh is the full [N,128] table; this half reads columns coff..coff+63.
// Accumulation loop unrolled x4 with prefetched gathers.
// ---------------------------------------------------------------------------
__global__ __launch_bounds__(256) void gat_agg_h(
    const float* __restrict__ xh, int coff, const float* __restrict__ alpha,
    const int* __restrict__ csr_ptr, const int* __restrict__ csr_edge,
    const int* __restrict__ src_idx, const float* __restrict__ conv_b_off,
    float* __restrict__ agg)
{
    int n = (blockIdx.x * 256 + threadIdx.x) >> 6;
    if (n >= N_NODES) return;
    int lane = threadIdx.x & 63;
    int c = coff + lane;
    int hd = lane >> 5;
    int start = csr_ptr[n], end = csr_ptr[n + 1];

    float m_run = -1e30f, d_run = 0.f, acc = 0.f;

    for (int base = start; base < end; base += 64) {
        int cnt = min(64, end - base);
        int e_l = 0, s_l = 0;
        if (lane < cnt) {
            e_l = csr_edge[base + lane];
            s_l = src_idx[e_l];
        }
        float a_t[2];
        float m_blk = -1e30f;
#pragma unroll
        for (int tt = 0; tt < 2; tt++) {
            int i = (lane & 31) + tt * 32;
            float a = -1e30f;
            if (i < cnt) {
                int e = __shfl(e_l, i);
                a = alpha[(size_t)e * 2 + hd];
            }
            a_t[tt] = a;
            m_blk = fmaxf(m_blk, a);
        }
#pragma unroll
        for (int off = 16; off >= 1; off >>= 1)
            m_blk = fmaxf(m_blk, __shfl_xor(m_blk, off, 32));
        float m_new = fmaxf(m_run, m_blk);
        float rescale = __expf(m_run - m_new);
        float dsum = __expf(a_t[0] - m_new) + __expf(a_t[1] - m_new);
#pragma unroll
        for (int off = 16; off >= 1; off >>= 1)
            dsum += __shfl_xor(dsum, off, 32);
        d_run = d_run * rescale + dsum;
        acc *= rescale;

        for (int i = 0; i < cnt; i += 4) {
            int e0 = __shfl(e_l, i + 0), s0 = __shfl(s_l, i + 0);
            int e1 = __shfl(e_l, i + 1), s1 = __shfl(s_l, i + 1);
            int e2 = __shfl(e_l, i + 2), s2 = __shfl(s_l, i + 2);
            int e3 = __shfl(e_l, i + 3), s3 = __shfl(s_l, i + 3);
            int rem = cnt - i;
            float x0 = xh[(size_t)s0 * H + c];
            float a0 = alpha[(size_t)e0 * 2 + hd];
            float x1 = 0.f, a1 = -1e30f;
            float x2 = 0.f, a2 = -1e30f;
            float x3 = 0.f, a3 = -1e30f;
            if (rem > 1) { x1 = xh[(size_t)s1 * H + c]; a1 = alpha[(size_t)e1 * 2 + hd]; }
            if (rem > 2) { x2 = xh[(size_t)s2 * H + c]; a2 = alpha[(size_t)e2 * 2 + hd]; }
            if (rem > 3) { x3 = xh[(size_t)s3 * H + c]; a3 = alpha[(size_t)e3 * 2 + hd]; }
            acc += x0 * __expf(a0 - m_new) + x1 * __expf(a1 - m_new)
                 + x2 * __expf(a2 - m_new) + x3 * __expf(a3 - m_new);
        }
        m_run = m_new;
    }
    float inv = 1.f / (d_run + 1e-16f);
    agg[(size_t)n * HQ + lane] = acc * inv + conv_b_off[lane];
}

// ---------------------------------------------------------------------------
// BatchNorm (per half, 64 channels)
// ---------------------------------------------------------------------------
__global__ __launch_bounds__(64) void bn_partial_h(const float* __restrict__ agg,
                                                   float* __restrict__ part)
{
    int b = blockIdx.x;   // 256 blocks
    int c = threadIdx.x;  // 64
    int per = (N_NODES + 255) / 256;
    int s = b * per, e = min(N_NODES, s + per);
    float sum = 0.f, sq = 0.f;
    for (int n = s; n < e; n++) {
        float v = agg[(size_t)n * HQ + c];
        sum += v; sq += v * v;
    }
    part[b * HQ + c] = sum;
    part[256 * HQ + b * HQ + c] = sq;
}

__global__ __launch_bounds__(256) void bn_finish_h(const float* __restrict__ part,
                                                   const float* __restrict__ gamma,
                                                   const float* __restrict__ beta,
                                                   float* __restrict__ scale,
                                                   float* __restrict__ shift)
{
    __shared__ double red[2][4][64];
    int c = threadIdx.x & 63;
    int g = threadIdx.x >> 6;  // 4 groups of 64 partial-blocks
    double s = 0.0, q = 0.0;
    for (int b = g * 64; b < (g + 1) * 64; b++) {
        s += (double)part[b * HQ + c];
        q += (double)part[256 * HQ + b * HQ + c];
    }
    red[0][g][c] = s;
    red[1][g][c] = q;
    __syncthreads();
    if (g == 0) {
        s = red[0][0][c] + red[0][1][c] + red[0][2][c] + red[0][3][c];
        q = red[1][0][c] + red[1][1][c] + red[1][2][c] + red[1][3][c];
        float mu = (float)(s / N_NODES);
        float var = (float)(q / N_NODES) - mu * mu;
        float rstd = rsqrtf(var + 1e-5f);
        float sc = gamma[c] * rstd;
        scale[c] = sc;
        shift[c] = beta[c] - mu * sc;
    }
}

__global__ __launch_bounds__(256) void bn_apply_h(const float* __restrict__ agg,
                                                  const float* __restrict__ scale,
                                                  const float* __restrict__ shift,
                                                  float* __restrict__ h, int coff)
{
    int i = blockIdx.x * 256 + threadIdx.x;  // over N*HQ/4
    if (i >= N_NODES * HQ / 4) return;
    int n = i >> 4;
    int c0 = (i & 15) * 4;
    float4 v = *(const float4*)&agg[(size_t)n * HQ + c0];
    float4 sc = *(const float4*)&scale[c0];
    float4 sh = *(const float4*)&shift[c0];
    float* hp = &h[(size_t)n * H + coff + c0];
    float4 hv = *(const float4*)hp;
    float4 o;
    o.x = fmaxf(v.x * sc.x + sh.x, 0.f) + hv.x;
    o.y = fmaxf(v.y * sc.y + sh.y, 0.f) + hv.y;
    o.z = fmaxf(v.z * sc.z + sh.z, 0.f) + hv.z;
    o.w = fmaxf(v.w * sc.w + sh.w, 0.f) + hv.w;
    *(float4*)hp = o;
}

// ---------------------------------------------------------------------------
// Graph head
// ---------------------------------------------------------------------------
__global__ __launch_bounds__(128) void graph_head(
    const float* __restrict__ nf, const int* __restrict__ gptr,
    const float* __restrict__ t_emb,
    const float* __restrict__ pW1, const float* __restrict__ pb1,
    const float* __restrict__ pW2, const float* __restrict__ pb2,
    const float* __restrict__ npW1, const float* __restrict__ npb1,
    float* __restrict__ tgW)
{
    int g = blockIdx.x, c = threadIdx.x;
    int s = gptr[g], e = gptr[g + 1];
    float sum = 0.f;
    for (int n = s; n < e; n++) sum += nf[(size_t)n * H + c];
    float cf = (e - s > 0) ? (float)(e - s) : 1.f;
    __shared__ float row[H], z[H];
    row[c] = sum / cf;
    __syncthreads();
    float a1 = pb1[c];
    for (int k = 0; k < H; k++) a1 += row[k] * pW1[k * H + c];
    z[c] = silu_f(a1);
    __syncthreads();
    float a2 = pb2[c];
    for (int k = 0; k < H; k++) a2 += z[k] * pW2[k * H + c];
    float tg = a2 + t_emb[g * H + c];
    __syncthreads();
    row[c] = tg;
    __syncthreads();
    float a3 = npb1[c];
    for (int k = 0; k < H; k++) a3 += row[k] * npW1[(size_t)(128 + k) * H + c];
    tgW[g * H + c] = a3;
}

// ---------------------------------------------------------------------------
extern "C" void kernel_launch(void* const* d_in, const int* in_sizes, int n_in,
                              void* d_out, int out_size, void* d_ws, size_t ws_size,
                              hipStream_t stream)
{
    const float* x          = (const float*)d_in[0];
    const int*   edge_index = (const int*)d_in[1];
    const float* edge_attr  = (const float*)d_in[2];
    const int*   batch      = (const int*)d_in[3];
    const int*   t          = (const int*)d_in[4];
    const float* atom_W     = (const float*)d_in[5];
    const float* atom_b     = (const float*)d_in[6];
    const float* bond_W     = (const float*)d_in[7];
    const float* bond_b     = (const float*)d_in[8];
    const float* lin_W      = (const float*)d_in[9];
    const float* edge_W     = (const float*)d_in[10];
    const float* att_src    = (const float*)d_in[11];
    const float* att_dst    = (const float*)d_in[12];
    const float* att_edge   = (const float*)d_in[13];
    const float* conv_b     = (const float*)d_in[14];
    const float* bn_gamma   = (const float*)d_in[15];
    const float* bn_beta    = (const float*)d_in[16];
    const float* out_W      = (const float*)d_in[17];
    const float* out_b      = (const float*)d_in[18];
    const float* time_W1    = (const float*)d_in[19];
    const float* time_b1    = (const float*)d_in[20];
    const float* time_W2    = (const float*)d_in[21];
    const float* time_b2    = (const float*)d_in[22];
    const float* pool_W1    = (const float*)d_in[23];
    const float* pool_b1    = (const float*)d_in[24];
    const float* pool_W2    = (const float*)d_in[25];
    const float* pool_b2    = (const float*)d_in[26];
    const float* np_W1      = (const float*)d_in[27];
    const float* np_b1      = (const float*)d_in[28];
    const float* np_W2      = (const float*)d_in[29];
    const float* np_b2      = (const float*)d_in[30];
    const float* np_W3      = (const float*)d_in[31];
    const float* np_b3      = (const float*)d_in[32];

    // ---------------- workspace layout (floats), total 71.6 MB ----------------
    const size_t OFF_H     = 0;                      // [N*H]
    const size_t OFF_XH    = 6400000;                // [N*H]
    const size_t OFF_AGG   = 12800000;               // [N*HQ]
    const size_t OFF_ALPHA = 16000000;               // [E*2]
    const size_t OFF_TEMB  = 17800000;               // [NB*H]
    const size_t OFF_TGW   = 17832768;               // [NB*H]
    const size_t OFF_MC    = 17865536;               // 256
    const size_t OFF_BNSC  = 17865792;               // 128
    const size_t OFF_BNSH  = 17865920;               // 128
    const size_t OFF_PART  = 17866048;               // 256*HQ*2 = 32768
    const size_t REQ_FLOATS = 17898816;
    const size_t REQ_BYTES  = REQ_FLOATS * 4;        // 71,595,264

    if (ws_size < REQ_BYTES) {
        hipMemsetAsync(d_out, 0, (size_t)out_size * sizeof(float), stream);
        return;
    }

    float* fws   = (float*)d_ws;
    float* h     = fws + OFF_H;
    float* xh    = fws + OFF_XH;
    float* agg   = fws + OFF_AGG;
    float* alpha = fws + OFF_ALPHA;
    float* t_emb = fws + OFF_TEMB;
    float* tgW   = fws + OFF_TGW;
    float* mc    = fws + OFF_MC;
    float* bnsc  = fws + OFF_BNSC;
    float* bnsh  = fws + OFF_BNSH;
    float* part  = fws + OFF_PART;

    // d_out scratch (1.95M floats = 7.8 MB): CSR ints + sS/sD.
    // All consumers finish before the final GEMM overwrites d_out.
    int* ib       = (int*)d_out;
    int* csr_ptr  = ib;                  // 50048
    int* csr_edge = ib + 50048;          // 800000
    int* deg      = ib + 850048;         // 50048 (also scatter cursor)
    int* gcnt     = ib + 900096;         // 256
    int* gptr     = ib + 900352;         // 257
    float* sS     = (float*)d_out + 900864;   // [N*4] = 200000
    float* sD     = (float*)d_out + 1100864;  // [N*4] = 200000 (end 1300864)

    hipMemsetAsync(deg, 0, N_NODES * sizeof(int), stream);
    hipMemsetAsync(gcnt, 0, NB * sizeof(int), stream);

    precompute_small<<<1, 256, 0, stream>>>(edge_W, att_edge, bond_W, bond_b, mc);
    time_embed<<<NB, 128, 0, stream>>>(t, time_W1, time_b1, time_W2, time_b2, t_emb);

    hist_dst<<<(N_EDGES + 255) / 256, 256, 0, stream>>>(edge_index, deg);
    hist_batch<<<(N_NODES + 255) / 256, 256, 0, stream>>>(batch, gcnt);
    scan_big<<<1, 1024, 0, stream>>>(deg, csr_ptr, N_NODES);
    scan_big<<<1, 1024, 0, stream>>>(gcnt, gptr, NB);
    hipMemsetAsync(deg, 0, N_NODES * sizeof(int), stream);
    scatter_edges<<<(N_EDGES + 255) / 256, 256, 0, stream>>>(edge_index, csr_ptr, deg, csr_edge);

    const int GB = (N_NODES + 63) / 64;  // gemm128 grid

    // h = x @ atom_W + atom_b
    gemm128<AD><<<GB, 256, 0, stream>>>(x, atom_W, atom_b, nullptr, nullptr,
                                        h, N_NODES, H, 0);

    for (int l = 0; l < LAYERS; l++) {
        // xh = h @ lin_W[l]  (full 128 cols)
        gemm128<H><<<GB, 256, 0, stream>>>(h, lin_W + (size_t)l * H * H, nullptr,
                                           nullptr, nullptr, xh, N_NODES, H, 0);
        attn_scores<<<N_NODES / 2, 256, 0, stream>>>(xh, att_src + l * H,
                                                     att_dst + l * H, sS, sD);
        for (int half = 0; half < 2; half++) {
            int hh0 = half * 2;
            int coff = half * HQ;
            edge_scores_h<<<(N_EDGES + 255) / 256, 256, 0, stream>>>(
                edge_attr, edge_index, mc + l * 44, hh0, sS, sD, alpha);
            gat_agg_h<<<N_NODES / 4, 256, 0, stream>>>(
                xh, coff, alpha, csr_ptr, csr_edge, edge_index,
                conv_b + l * H + coff, agg);
            bn_partial_h<<<256, 64, 0, stream>>>(agg, part);
            bn_finish_h<<<1, 256, 0, stream>>>(part, bn_gamma + l * H + coff,
                                               bn_beta + l * H + coff, bnsc, bnsh);
            bn_apply_h<<<(N_NODES * HQ / 4 + 255) / 256, 256, 0, stream>>>(
                agg, bnsc, bnsh, h, coff);
        }
    }

    // node_features = h @ out_W + out_b  -> xh
    gemm128<H><<<GB, 256, 0, stream>>>(h, out_W, out_b, nullptr, nullptr,
                                       xh, N_NODES, H, 0);

    graph_head<<<NB, 128, 0, stream>>>(xh, gptr, t_emb, pool_W1, pool_b1,
                                       pool_W2, pool_b2, np_W1, np_b1, tgW);

    // z1 = silu(nf @ np_W1[0:128] + tgW[batch]) -> h
    gemm128<H><<<GB, 256, 0, stream>>>(xh, np_W1, nullptr, tgW, batch,
                                       h, N_NODES, H, 1);
    // z2 = silu(z1 @ np_W2 + np_b2) -> xh
    gemm128<H><<<GB, 256, 0, stream>>>(h, np_W2, np_b2, nullptr, nullptr,
                                       xh, N_NODES, H, 1);
    // out = z2 @ np_W3 + np_b3 -> d_out [N,39]  (overwrites scratch, now dead)
    {
        int NCG = (AD + 3) / 4;             // 10
        int NPB = (256 / NCG) * 4;          // 100
        size_t sh = (size_t)H * (NPB + 4) * sizeof(float);
        int blocks = (N_NODES + NPB - 1) / NPB;
        node_gemm<<<blocks, 256, sh, stream>>>(xh, np_W3, np_b3, (float*)d_out,
                                               N_NODES, H, AD, AD, NPB, NCG);
    }
}

// Round 6
// 1131.330 us; speedup vs baseline: 1.7665x; 1.3287x over previous
//
#include <hip/hip_runtime.h>
#include <math.h>

#define N_NODES 50000
#define N_EDGES 800000
#define NB 256
#define AD 39
#define BD 10
#define H 128
#define HQ 64
#define HEADS 4
#define HD 32
#define LAYERS 3
#define TD 128

__device__ __forceinline__ float silu_f(float x) { return x / (1.f + __expf(-x)); }

// ---------------------------------------------------------------------------
// Specialized GEMM: out[N,128] = act(A[N,KT] @ W[KT,128](ldw) + bias
//                                    + bias2[gidx[n]])
// ---------------------------------------------------------------------------
__device__ __forceinline__ void fma_rank1(float acc[8][4], float4 aL, float4 aH, float4 w)
{
    float ar[8] = {aL.x, aL.y, aL.z, aL.w, aH.x, aH.y, aH.z, aH.w};
    float wr[4] = {w.x, w.y, w.z, w.w};
#pragma unroll
    for (int r = 0; r < 8; r++)
#pragma unroll
        for (int j = 0; j < 4; j++) acc[r][j] += ar[r] * wr[j];
}

template<int KT>
__global__ __launch_bounds__(256) void gemm128(
    const float* __restrict__ A, const float* __restrict__ W,
    const float* __restrict__ bias, const float* __restrict__ bias2,
    const int* __restrict__ gidx, float* __restrict__ out,
    int Nrows, int ldw, int act)
{
    __shared__ float As[KT * 68];
    const int tid = threadIdx.x;
    const int rowBase = blockIdx.x * 64;

    for (int idx = tid; idx < 64 * KT; idx += 256) {
        int row = idx / KT;
        int k = idx - row * KT;
        int n = rowBase + row;
        As[k * 68 + row] = (n < Nrows) ? A[(size_t)n * KT + k] : 0.f;
    }
    __syncthreads();

    const int c0 = (tid & 31) * 4;
    const int n0 = (tid >> 5) * 8;

    float acc[8][4];
#pragma unroll
    for (int r = 0; r < 8; r++)
#pragma unroll
        for (int j = 0; j < 4; j++) acc[r][j] = 0.f;

    const float* wp = W + c0;
    int k = 0;
    for (; k + 4 <= KT; k += 4) {
        float4 w0 = *(const float4*)&wp[(size_t)(k + 0) * ldw];
        float4 w1 = *(const float4*)&wp[(size_t)(k + 1) * ldw];
        float4 w2 = *(const float4*)&wp[(size_t)(k + 2) * ldw];
        float4 w3 = *(const float4*)&wp[(size_t)(k + 3) * ldw];
        float4 aL0 = *(const float4*)&As[(k + 0) * 68 + n0];
        float4 aH0 = *(const float4*)&As[(k + 0) * 68 + n0 + 4];
        float4 aL1 = *(const float4*)&As[(k + 1) * 68 + n0];
        float4 aH1 = *(const float4*)&As[(k + 1) * 68 + n0 + 4];
        float4 aL2 = *(const float4*)&As[(k + 2) * 68 + n0];
        float4 aH2 = *(const float4*)&As[(k + 2) * 68 + n0 + 4];
        float4 aL3 = *(const float4*)&As[(k + 3) * 68 + n0];
        float4 aH3 = *(const float4*)&As[(k + 3) * 68 + n0 + 4];
        fma_rank1(acc, aL0, aH0, w0);
        fma_rank1(acc, aL1, aH1, w1);
        fma_rank1(acc, aL2, aH2, w2);
        fma_rank1(acc, aL3, aH3, w3);
    }
    for (; k < KT; ++k) {
        float4 w0 = *(const float4*)&wp[(size_t)k * ldw];
        float4 aL = *(const float4*)&As[k * 68 + n0];
        float4 aH = *(const float4*)&As[k * 68 + n0 + 4];
        fma_rank1(acc, aL, aH, w0);
    }

    float4 bv = make_float4(0.f, 0.f, 0.f, 0.f);
    if (bias) bv = *(const float4*)&bias[c0];
#pragma unroll
    for (int r = 0; r < 8; r++) {
        int n = rowBase + n0 + r;
        if (n >= Nrows) break;
        float4 o;
        o.x = acc[r][0] + bv.x;
        o.y = acc[r][1] + bv.y;
        o.z = acc[r][2] + bv.z;
        o.w = acc[r][3] + bv.w;
        if (bias2) {
            float4 b2 = *(const float4*)&bias2[(size_t)gidx[n] * H + c0];
            o.x += b2.x; o.y += b2.y; o.z += b2.z; o.w += b2.w;
        }
        if (act) {
            o.x = silu_f(o.x); o.y = silu_f(o.y);
            o.z = silu_f(o.z); o.w = silu_f(o.w);
        }
        *(float4*)&out[(size_t)n * H + c0] = o;
    }
}

// ---------------------------------------------------------------------------
// Final GEMM: out[N,39] = A[N,128] @ W[128,39] + bias.  K compile-time,
// unrolled x4.  NPB=100 rows, NCG=10 col-groups.
// ---------------------------------------------------------------------------
__global__ __launch_bounds__(256) void gemm_out39(
    const float* __restrict__ A, const float* __restrict__ W,
    const float* __restrict__ bias, float* __restrict__ out, int Nrows)
{
    const int K = 128, OC = AD, NPB = 100, NCG = 10, APAD = 104;
    __shared__ float A_lds[K * APAD];
    const int tid = threadIdx.x;
    const int rowBase = blockIdx.x * NPB;

    for (int idx = tid; idx < NPB * K; idx += 256) {
        int node = idx >> 7;
        int k = idx & 127;
        int n = rowBase + node;
        A_lds[k * APAD + node] = (n < Nrows) ? A[(size_t)n * K + k] : 0.f;
    }
    __syncthreads();

    const int cg = tid % NCG;
    const int ng = tid / NCG;
    const int c0 = cg * 4, n0 = ng * 4;
    if (n0 >= NPB) return;

    float acc[16];
#pragma unroll
    for (int i = 0; i < 16; i++) acc[i] = 0.f;

#pragma unroll 4
    for (int k = 0; k < K; k++) {
        float4 a = *(const float4*)&A_lds[k * APAD + n0];
        size_t base = (size_t)k * OC + c0;
        float w0 = W[base + 0];
        float w1 = (c0 + 1 < OC) ? W[base + 1] : 0.f;
        float w2 = (c0 + 2 < OC) ? W[base + 2] : 0.f;
        float w3 = (c0 + 3 < OC) ? W[base + 3] : 0.f;
        acc[0]  += a.x * w0; acc[1]  += a.x * w1; acc[2]  += a.x * w2; acc[3]  += a.x * w3;
        acc[4]  += a.y * w0; acc[5]  += a.y * w1; acc[6]  += a.y * w2; acc[7]  += a.y * w3;
        acc[8]  += a.z * w0; acc[9]  += a.z * w1; acc[10] += a.z * w2; acc[11] += a.z * w3;
        acc[12] += a.w * w0; acc[13] += a.w * w1; acc[14] += a.w * w2; acc[15] += a.w * w3;
    }

#pragma unroll
    for (int i = 0; i < 4; i++) {
        int n = rowBase + n0 + i;
        if (n >= Nrows) continue;
#pragma unroll
        for (int j = 0; j < 4; j++) {
            int c = c0 + j;
            if (c >= OC) continue;
            out[(size_t)n * OC + c] = acc[i * 4 + j] + bias[c];
        }
    }
}

// ---------------------------------------------------------------------------
// Fold edge path coefficients
// ---------------------------------------------------------------------------
__global__ __launch_bounds__(256) void precompute_small(
    const float* __restrict__ edge_W, const float* __restrict__ att_edge,
    const float* __restrict__ bond_W, const float* __restrict__ bond_b,
    float* __restrict__ mc)
{
    __shared__ float bl[LAYERS][H][4];
    int tid = threadIdx.x;
    for (int task = tid; task < LAYERS * H; task += 256) {
        int l = task / H, k = task % H;
#pragma unroll
        for (int hh = 0; hh < 4; hh++) {
            float s = 0.f;
            for (int d = 0; d < HD; d++)
                s += edge_W[(size_t)l * H * H + k * H + hh * HD + d] *
                     att_edge[l * H + hh * HD + d];
            bl[l][k][hh] = s;
        }
    }
    __syncthreads();
    if (tid < LAYERS * BD * 4) {
        int l = tid / (BD * 4), r = tid % (BD * 4), j = r / 4, hh = r % 4;
        float s = 0.f;
        for (int k = 0; k < H; k++) s += bond_W[j * H + k] * bl[l][k][hh];
        mc[l * 44 + j * 4 + hh] = s;
    }
    if (tid >= 128 && tid < 128 + LAYERS * 4) {
        int r = tid - 128, l = r / 4, hh = r % 4;
        float s = 0.f;
        for (int k = 0; k < H; k++) s += bond_b[k] * bl[l][k][hh];
        mc[l * 44 + 40 + hh] = s;
    }
}

// ---------------------------------------------------------------------------
__global__ __launch_bounds__(128) void time_embed(
    const int* __restrict__ t,
    const float* __restrict__ W1, const float* __restrict__ b1,
    const float* __restrict__ W2, const float* __restrict__ b2,
    float* __restrict__ t_emb)
{
    int g = blockIdx.x, c = threadIdx.x;
    float tf = (float)t[g];
    __shared__ float emb[TD], z[H];
    int k = c & 63;
    float f = __expf(-9.210340371976184f * (float)k / 63.0f);
    float e = tf * f;
    emb[c] = (c < 64) ? sinf(e) : cosf(e);
    __syncthreads();
    float a1 = b1[c];
    for (int kk = 0; kk < TD; kk++) a1 += emb[kk] * W1[kk * H + c];
    z[c] = silu_f(a1);
    __syncthreads();
    float a2 = b2[c];
    for (int kk = 0; kk < H; kk++) a2 += z[kk] * W2[kk * H + c];
    t_emb[g * H + c] = a2;
}

// ---------------------------------------------------------------------------
// CSR build: histograms + multi-block scan + scatter (stores rank)
// ---------------------------------------------------------------------------
__global__ __launch_bounds__(256) void hist_dst(const int* __restrict__ edge_index,
                                                int* __restrict__ deg)
{
    int e = blockIdx.x * 256 + threadIdx.x;
    if (e < N_EDGES) atomicAdd(&deg[edge_index[N_EDGES + e]], 1);
}

__global__ __launch_bounds__(256) void hist_batch(const int* __restrict__ batch,
                                                  int* __restrict__ gcnt)
{
    int n = blockIdx.x * 256 + threadIdx.x;
    if (n < N_NODES) atomicAdd(&gcnt[batch[n]], 1);
}

__global__ __launch_bounds__(256) void scan_part(const int* __restrict__ cnt,
                                                 int* __restrict__ bsum, int n)
{
    int tid = threadIdx.x;
    int i0 = blockIdx.x * 1024 + tid * 4;
    int s = 0;
#pragma unroll
    for (int j = 0; j < 4; j++) if (i0 + j < n) s += cnt[i0 + j];
    __shared__ int red[256];
    red[tid] = s;
    __syncthreads();
    for (int off = 128; off >= 1; off >>= 1) {
        if (tid < off) red[tid] += red[tid + off];
        __syncthreads();
    }
    if (tid == 0) bsum[blockIdx.x] = red[0];
}

__global__ __launch_bounds__(256) void scan_tops(const int* __restrict__ bsum,
                                                 int* __restrict__ boff, int G,
                                                 int* __restrict__ total)
{
    int tid = threadIdx.x;
    int v = (tid < G) ? bsum[tid] : 0;
    __shared__ int ps[256];
    ps[tid] = v;
    __syncthreads();
    for (int off = 1; off < 256; off <<= 1) {
        int t = (tid >= off) ? ps[tid - off] : 0;
        __syncthreads();
        ps[tid] += t;
        __syncthreads();
    }
    if (tid < G) boff[tid] = ps[tid] - v;
    if (tid == 255) *total = ps[255];
}

__global__ __launch_bounds__(256) void scan_final(const int* __restrict__ cnt,
                                                  const int* __restrict__ boff,
                                                  int* __restrict__ ptr, int n)
{
    int tid = threadIdx.x;
    int i0 = blockIdx.x * 1024 + tid * 4;
    int v[4];
#pragma unroll
    for (int j = 0; j < 4; j++) v[j] = (i0 + j < n) ? cnt[i0 + j] : 0;
    int s = v[0] + v[1] + v[2] + v[3];
    __shared__ int ps[256];
    ps[tid] = s;
    __syncthreads();
    for (int off = 1; off < 256; off <<= 1) {
        int t = (tid >= off) ? ps[tid - off] : 0;
        __syncthreads();
        ps[tid] += t;
        __syncthreads();
    }
    int run = boff[blockIdx.x] + ps[tid] - s;
#pragma unroll
    for (int j = 0; j < 4; j++) {
        if (i0 + j < n) { ptr[i0 + j] = run; run += v[j]; }
    }
}

__global__ __launch_bounds__(256) void scatter_edges(const int* __restrict__ edge_index,
                                                     const int* __restrict__ ptr,
                                                     int* __restrict__ cursor,
                                                     int* __restrict__ src_csr,
                                                     int* __restrict__ rank)
{
    int e = blockIdx.x * 256 + threadIdx.x;
    if (e >= N_EDGES) return;
    int s = edge_index[e];
    int d = edge_index[N_EDGES + e];
    int pos = atomicAdd(&cursor[d], 1);
    int p = ptr[d] + pos;
    src_csr[p] = s;
    rank[e] = p;
}

// ---------------------------------------------------------------------------
// Attention scores, all 4 heads: 2 nodes per 256-thr block.
// ---------------------------------------------------------------------------
__global__ __launch_bounds__(256) void attn_scores(
    const float* __restrict__ xh, const float* __restrict__ att_src,
    const float* __restrict__ att_dst, float* __restrict__ s_src,
    float* __restrict__ s_dst)
{
    int tid = threadIdx.x;
    int n = blockIdx.x * 2 + (tid >> 7);
    int c = tid & 127;
    float v = xh[(size_t)n * H + c];
    float as = v * att_src[c];
    float ad = v * att_dst[c];
#pragma unroll
    for (int off = 16; off >= 1; off >>= 1) {
        as += __shfl_xor(as, off, 32);
        ad += __shfl_xor(ad, off, 32);
    }
    if ((c & 31) == 0) {
        s_src[n * 4 + (c >> 5)] = as;
        s_dst[n * 4 + (c >> 5)] = ad;
    }
}

// ---------------------------------------------------------------------------
// Per-edge scores for one half, written DIRECTLY IN CSR ORDER via rank[e].
// ---------------------------------------------------------------------------
__global__ __launch_bounds__(256) void edge_scores_h(
    const float* __restrict__ edge_attr, const int* __restrict__ edge_index,
    const int* __restrict__ rank, const float* __restrict__ mc_l, int hh0,
    const float* __restrict__ sS, const float* __restrict__ sD,
    float* __restrict__ alpha)
{
    __shared__ float Ml[BD * 2], cl2[2];
    int tid = threadIdx.x;
    if (tid < BD * 2) Ml[tid] = mc_l[(tid >> 1) * 4 + hh0 + (tid & 1)];
    if (tid >= 32 && tid < 34) cl2[tid - 32] = mc_l[40 + hh0 + (tid - 32)];
    __syncthreads();
    int e = blockIdx.x * 256 + tid;
    if (e >= N_EDGES) return;
    float se0 = cl2[0], se1 = cl2[1];
#pragma unroll
    for (int j = 0; j < BD; j++) {
        float x = edge_attr[(size_t)e * BD + j];
        se0 += x * Ml[j * 2 + 0];
        se1 += x * Ml[j * 2 + 1];
    }
    int s = edge_index[e];
    int d = edge_index[N_EDGES + e];
    float a;
    float2 o;
    a = sS[s * 4 + hh0]     + sD[d * 4 + hh0]     + se0; o.x = (a >= 0.f) ? a : 0.2f * a;
    a = sS[s * 4 + hh0 + 1] + sD[d * 4 + hh0 + 1] + se1; o.y = (a >= 0.f) ? a : 0.2f * a;
    int p = rank[e];
    *(float2*)&alpha[(size_t)p * 2] = o;
}

// ---------------------------------------------------------------------------
// GAT aggregation for one half: one wave per dst node, online softmax.
// alpha and src_csr are in CSR order -> coalesced streams.  Softmax weights
// redistributed by shuffle (no per-edge alpha re-reads).
// ---------------------------------------------------------------------------
__global__ __launch_bounds__(256) void gat_agg_h(
    const float* __restrict__ xh, int coff, const float* __restrict__ alpha,
    const int* __restrict__ csr_ptr, const int* __restrict__ src_csr,
    const float* __restrict__ conv_b_off, float* __restrict__ agg)
{
    int n = (blockIdx.x * 256 + threadIdx.x) >> 6;
    if (n >= N_NODES) return;
    int lane = threadIdx.x & 63;
    int c = coff + lane;
    int hd = lane >> 5;
    int start = csr_ptr[n], end = csr_ptr[n + 1];

    float m_run = -1e30f, d_run = 0.f, acc = 0.f;

    for (int base = start; base < end; base += 64) {
        int cnt = min(64, end - base);
        int s_l = (lane < cnt) ? src_csr[base + lane] : 0;
        int i0 = lane & 31;
        float a0 = (i0 < cnt)      ? alpha[(size_t)(base + i0) * 2 + hd]      : -1e30f;
        float a1 = (i0 + 32 < cnt) ? alpha[(size_t)(base + i0 + 32) * 2 + hd] : -1e30f;

        float m_blk = fmaxf(a0, a1);
#pragma unroll
        for (int off = 16; off >= 1; off >>= 1)
            m_blk = fmaxf(m_blk, __shfl_xor(m_blk, off, 32));
        float m_new = fmaxf(m_run, m_blk);
        float rescale = __expf(m_run - m_new);
        float e0 = __expf(a0 - m_new);
        float e1 = __expf(a1 - m_new);
        float dsum = e0 + e1;
#pragma unroll
        for (int off = 16; off >= 1; off >>= 1)
            dsum += __shfl_xor(dsum, off, 32);
        d_run = d_run * rescale + dsum;
        acc *= rescale;

        int c1 = min(cnt, 32);
        for (int i = 0; i < c1; i += 4) {
            int s0 = __shfl(s_l, i + 0), s1 = __shfl(s_l, i + 1);
            int s2 = __shfl(s_l, i + 2), s3 = __shfl(s_l, i + 3);
            float w0 = __shfl(e0, i + 0, 32), w1 = __shfl(e0, i + 1, 32);
            float w2 = __shfl(e0, i + 2, 32), w3 = __shfl(e0, i + 3, 32);
            float x0 = xh[(size_t)s0 * H + c];
            float x1 = xh[(size_t)s1 * H + c];
            float x2 = xh[(size_t)s2 * H + c];
            float x3 = xh[(size_t)s3 * H + c];
            acc += x0 * w0 + x1 * w1 + x2 * w2 + x3 * w3;
        }
        for (int i = 32; i < cnt; i += 4) {
            int s0 = __shfl(s_l, i + 0), s1 = __shfl(s_l, i + 1);
            int s2 = __shfl(s_l, i + 2), s3 = __shfl(s_l, i + 3);
            float w0 = __shfl(e1, i - 32, 32), w1 = __shfl(e1, i - 31, 32);
            float w2 = __shfl(e1, i - 30, 32), w3 = __shfl(e1, i - 29, 32);
            float x0 = xh[(size_t)s0 * H + c];
            float x1 = xh[(size_t)s1 * H + c];
            float x2 = xh[(size_t)s2 * H + c];
            float x3 = xh[(size_t)s3 * H + c];
            acc += x0 * w0 + x1 * w1 + x2 * w2 + x3 * w3;
        }
        m_run = m_new;
    }
    float inv = 1.f / (d_run + 1e-16f);
    agg[(size_t)n * HQ + lane] = acc * inv + conv_b_off[lane];
}

// ---------------------------------------------------------------------------
// BatchNorm (per half, 64 channels)
// ---------------------------------------------------------------------------
__global__ __launch_bounds__(256) void bn_partial_h(const float* __restrict__ agg,
                                                    float* __restrict__ part)
{
    __shared__ float red[2][4][64];
    int b = blockIdx.x;   // 256 blocks
    int c = threadIdx.x & 63;
    int q = threadIdx.x >> 6;  // 4 row-quarters
    int per = (N_NODES + 255) / 256;
    int s = b * per, e = min(N_NODES, s + per);
    int qs = s + q * ((per + 3) / 4);
    int qe = min(e, qs + (per + 3) / 4);
    float sum = 0.f, sq = 0.f;
    for (int n = qs; n < qe; n++) {
        float v = agg[(size_t)n * HQ + c];
        sum += v; sq += v * v;
    }
    red[0][q][c] = sum;
    red[1][q][c] = sq;
    __syncthreads();
    if (q == 0) {
        sum = red[0][0][c] + red[0][1][c] + red[0][2][c] + red[0][3][c];
        sq  = red[1][0][c] + red[1][1][c] + red[1][2][c] + red[1][3][c];
        part[b * HQ + c] = sum;
        part[256 * HQ + b * HQ + c] = sq;
    }
}

__global__ __launch_bounds__(256) void bn_finish_h(const float* __restrict__ part,
                                                   const float* __restrict__ gamma,
                                                   const float* __restrict__ beta,
                                                   float* __restrict__ scale,
                                                   float* __restrict__ shift)
{
    __shared__ double red[2][4][64];
    int c = threadIdx.x & 63;
    int g = threadIdx.x >> 6;
    double s = 0.0, q = 0.0;
    for (int b = g * 64; b < (g + 1) * 64; b++) {
        s += (double)part[b * HQ + c];
        q += (double)part[256 * HQ + b * HQ + c];
    }
    red[0][g][c] = s;
    red[1][g][c] = q;
    __syncthreads();
    if (g == 0) {
        s = red[0][0][c] + red[0][1][c] + red[0][2][c] + red[0][3][c];
        q = red[1][0][c] + red[1][1][c] + red[1][2][c] + red[1][3][c];
        float mu = (float)(s / N_NODES);
        float var = (float)(q / N_NODES) - mu * mu;
        float rstd = rsqrtf(var + 1e-5f);
        float sc = gamma[c] * rstd;
        scale[c] = sc;
        shift[c] = beta[c] - mu * sc;
    }
}

__global__ __launch_bounds__(256) void bn_apply_h(const float* __restrict__ agg,
                                                  const float* __restrict__ scale,
                                                  const float* __restrict__ shift,
                                                  float* __restrict__ h, int coff)
{
    int i = blockIdx.x * 256 + threadIdx.x;  // over N*HQ/4
    if (i >= N_NODES * HQ / 4) return;
    int n = i >> 4;
    int c0 = (i & 15) * 4;
    float4 v = *(const float4*)&agg[(size_t)n * HQ + c0];
    float4 sc = *(const float4*)&scale[c0];
    float4 sh = *(const float4*)&shift[c0];
    float* hp = &h[(size_t)n * H + coff + c0];
    float4 hv = *(const float4*)hp;
    float4 o;
    o.x = fmaxf(v.x * sc.x + sh.x, 0.f) + hv.x;
    o.y = fmaxf(v.y * sc.y + sh.y, 0.f) + hv.y;
    o.z = fmaxf(v.z * sc.z + sh.z, 0.f) + hv.z;
    o.w = fmaxf(v.w * sc.w + sh.w, 0.f) + hv.w;
    *(float4*)hp = o;
}

// ---------------------------------------------------------------------------
// Graph head
// ---------------------------------------------------------------------------
__global__ __launch_bounds__(128) void graph_head(
    const float* __restrict__ nf, const int* __restrict__ gptr,
    const float* __restrict__ t_emb,
    const float* __restrict__ pW1, const float* __restrict__ pb1,
    const float* __restrict__ pW2, const float* __restrict__ pb2,
    const float* __restrict__ npW1, const float* __restrict__ npb1,
    float* __restrict__ tgW)
{
    int g = blockIdx.x, c = threadIdx.x;
    int s = gptr[g], e = gptr[g + 1];
    float sum = 0.f;
    for (int n = s; n < e; n++) sum += nf[(size_t)n * H + c];
    float cf = (e - s > 0) ? (float)(e - s) : 1.f;
    __shared__ float row[H], z[H];
    row[c] = sum / cf;
    __syncthreads();
    float a1 = pb1[c];
    for (int k = 0; k < H; k++) a1 += row[k] * pW1[k * H + c];
    z[c] = silu_f(a1);
    __syncthreads();
    float a2 = pb2[c];
    for (int k = 0; k < H; k++) a2 += z[k] * pW2[k * H + c];
    float tg = a2 + t_emb[g * H + c];
    __syncthreads();
    row[c] = tg;
    __syncthreads();
    float a3 = npb1[c];
    for (int k = 0; k < H; k++) a3 += row[k] * npW1[(size_t)(128 + k) * H + c];
    tgW[g * H + c] = a3;
}

// ---------------------------------------------------------------------------
extern "C" void kernel_launch(void* const* d_in, const int* in_sizes, int n_in,
                              void* d_out, int out_size, void* d_ws, size_t ws_size,
                              hipStream_t stream)
{
    const float* x          = (const float*)d_in[0];
    const int*   edge_index = (const int*)d_in[1];
    const float* edge_attr  = (const float*)d_in[2];
    const int*   batch      = (const int*)d_in[3];
    const int*   t          = (const int*)d_in[4];
    const float* atom_W     = (const float*)d_in[5];
    const float* atom_b     = (const float*)d_in[6];
    const float* bond_W     = (const float*)d_in[7];
    const float* bond_b     = (const float*)d_in[8];
    const float* lin_W      = (const float*)d_in[9];
    const float* edge_W     = (const float*)d_in[10];
    const float* att_src    = (const float*)d_in[11];
    const float* att_dst    = (const float*)d_in[12];
    const float* att_edge   = (const float*)d_in[13];
    const float* conv_b     = (const float*)d_in[14];
    const float* bn_gamma   = (const float*)d_in[15];
    const float* bn_beta    = (const float*)d_in[16];
    const float* out_W      = (const float*)d_in[17];
    const float* out_b      = (const float*)d_in[18];
    const float* time_W1    = (const float*)d_in[19];
    const float* time_b1    = (const float*)d_in[20];
    const float* time_W2    = (const float*)d_in[21];
    const float* time_b2    = (const float*)d_in[22];
    const float* pool_W1    = (const float*)d_in[23];
    const float* pool_b1    = (const float*)d_in[24];
    const float* pool_W2    = (const float*)d_in[25];
    const float* pool_b2    = (const float*)d_in[26];
    const float* np_W1      = (const float*)d_in[27];
    const float* np_b1      = (const float*)d_in[28];
    const float* np_W2      = (const float*)d_in[29];
    const float* np_b2      = (const float*)d_in[30];
    const float* np_W3      = (const float*)d_in[31];
    const float* np_b3      = (const float*)d_in[32];

    // ---------------- workspace layout (floats), total 71.6 MB ----------------
    const size_t OFF_H     = 0;                      // [N*H]
    const size_t OFF_XH    = 6400000;                // [N*H]
    const size_t OFF_AGG   = 12800000;               // [N*HQ]
    const size_t OFF_ALPHA = 16000000;               // [E*2] = 1,600,000
    const size_t OFF_SD    = 17600000;               // [N*4] = 200,000
    const size_t OFF_TEMB  = 17800000;               // [NB*H]
    const size_t OFF_TGW   = 17832768;               // [NB*H]
    const size_t OFF_MC    = 17865536;               // 256
    const size_t OFF_BNSC  = 17865792;               // 128
    const size_t OFF_BNSH  = 17865920;               // 128
    const size_t OFF_PART  = 17866048;               // 256*HQ*2 = 32768
    const size_t REQ_FLOATS = 17898816;
    const size_t REQ_BYTES  = REQ_FLOATS * 4;        // 71,595,264 (proven OK)

    if (ws_size < REQ_BYTES) {
        hipMemsetAsync(d_out, 0, (size_t)out_size * sizeof(float), stream);
        return;
    }

    float* fws   = (float*)d_ws;
    float* h     = fws + OFF_H;
    float* xh    = fws + OFF_XH;
    float* agg   = fws + OFF_AGG;
    float* alpha = fws + OFF_ALPHA;
    float* sD    = fws + OFF_SD;
    float* t_emb = fws + OFF_TEMB;
    float* tgW   = fws + OFF_TGW;
    float* mc    = fws + OFF_MC;
    float* bnsc  = fws + OFF_BNSC;
    float* bnsh  = fws + OFF_BNSH;
    float* part  = fws + OFF_PART;

    // d_out scratch (1,950,000 floats): CSR ints + rank + sS.
    // All consumers finish before the final GEMM overwrites d_out.
    int* ib       = (int*)d_out;
    int* csr_ptr  = ib;                    // 50,016 (N+1 used)
    int* src_csr  = ib + 50016;            // 800,000
    int* rank     = ib + 850016;           // 800,000
    int* deg      = ib + 1650016;          // 50,016 (hist + scatter cursor)
    int* gcnt     = ib + 1700032;          // 256
    int* gptr     = ib + 1700288;          // 260 (B+1 used)
    int* bsum     = ib + 1700548;          // 64
    int* boff     = ib + 1700612;          // 64
    float* sS     = (float*)d_out + 1700676;  // [N*4] = 200,000 (end 1,900,676)

    hipMemsetAsync(deg, 0, N_NODES * sizeof(int), stream);
    hipMemsetAsync(gcnt, 0, NB * sizeof(int), stream);

    precompute_small<<<1, 256, 0, stream>>>(edge_W, att_edge, bond_W, bond_b, mc);
    time_embed<<<NB, 128, 0, stream>>>(t, time_W1, time_b1, time_W2, time_b2, t_emb);

    hist_dst<<<(N_EDGES + 255) / 256, 256, 0, stream>>>(edge_index, deg);
    hist_batch<<<(N_NODES + 255) / 256, 256, 0, stream>>>(batch, gcnt);

    const int GSN = (N_NODES + 1023) / 1024;  // 49
    scan_part<<<GSN, 256, 0, stream>>>(deg, bsum, N_NODES);
    scan_tops<<<1, 256, 0, stream>>>(bsum, boff, GSN, &csr_ptr[N_NODES]);
    scan_final<<<GSN, 256, 0, stream>>>(deg, boff, csr_ptr, N_NODES);

    scan_part<<<1, 256, 0, stream>>>(gcnt, bsum, NB);
    scan_tops<<<1, 256, 0, stream>>>(bsum, boff, 1, &gptr[NB]);
    scan_final<<<1, 256, 0, stream>>>(gcnt, boff, gptr, NB);

    hipMemsetAsync(deg, 0, N_NODES * sizeof(int), stream);
    scatter_edges<<<(N_EDGES + 255) / 256, 256, 0, stream>>>(edge_index, csr_ptr,
                                                             deg, src_csr, rank);

    const int GB = (N_NODES + 63) / 64;  // gemm128 grid

    // h = x @ atom_W + atom_b
    gemm128<AD><<<GB, 256, 0, stream>>>(x, atom_W, atom_b, nullptr, nullptr,
                                        h, N_NODES, H, 0);

    for (int l = 0; l < LAYERS; l++) {
        gemm128<H><<<GB, 256, 0, stream>>>(h, lin_W + (size_t)l * H * H, nullptr,
                                           nullptr, nullptr, xh, N_NODES, H, 0);
        attn_scores<<<N_NODES / 2, 256, 0, stream>>>(xh, att_src + l * H,
                                                     att_dst + l * H, sS, sD);
        for (int half = 0; half < 2; half++) {
            int hh0 = half * 2;
            int coff = half * HQ;
            edge_scores_h<<<(N_EDGES + 255) / 256, 256, 0, stream>>>(
                edge_attr, edge_index, rank, mc + l * 44, hh0, sS, sD, alpha);
            gat_agg_h<<<N_NODES / 4, 256, 0, stream>>>(
                xh, coff, alpha, csr_ptr, src_csr, conv_b + l * H + coff, agg);
            bn_partial_h<<<256, 256, 0, stream>>>(agg, part);
            bn_finish_h<<<1, 256, 0, stream>>>(part, bn_gamma + l * H + coff,
                                               bn_beta + l * H + coff, bnsc, bnsh);
            bn_apply_h<<<(N_NODES * HQ / 4 + 255) / 256, 256, 0, stream>>>(
                agg, bnsc, bnsh, h, coff);
        }
    }

    // node_features = h @ out_W + out_b  -> xh
    gemm128<H><<<GB, 256, 0, stream>>>(h, out_W, out_b, nullptr, nullptr,
                                       xh, N_NODES, H, 0);

    graph_head<<<NB, 128, 0, stream>>>(xh, gptr, t_emb, pool_W1, pool_b1,
                                       pool_W2, pool_b2, np_W1, np_b1, tgW);

    // z1 = silu(nf @ np_W1[0:128] + tgW[batch]) -> h
    gemm128<H><<<GB, 256, 0, stream>>>(xh, np_W1, nullptr, tgW, batch,
                                       h, N_NODES, H, 1);
    // z2 = silu(z1 @ np_W2 + np_b2) -> xh
    gemm128<H><<<GB, 256, 0, stream>>>(h, np_W2, np_b2, nullptr, nullptr,
                                       xh, N_NODES, H, 1);
    // out = z2 @ np_W3 + np_b3 -> d_out [N,39]  (overwrites scratch, now dead)
    gemm_out39<<<(N_NODES + 99) / 100, 256, 0, stream>>>(xh, np_W3, np_b3,
                                                         (float*)d_out, N_NODES);
}

// Round 7
// 979.155 us; speedup vs baseline: 2.0411x; 1.1554x over previous
//
#include <hip/hip_runtime.h>
#include <hip/hip_fp16.h>
#include <math.h>

#define N_NODES 50000
#define N_EDGES 800000
#define NB 256
#define AD 39
#define BD 10
#define H 128
#define HQ 64
#define HEADS 4
#define HD 32
#define LAYERS 3
#define TD 128

__device__ __forceinline__ float silu_f(float x) { return x / (1.f + __expf(-x)); }

// ---------------------------------------------------------------------------
// Specialized GEMM: out[N,128] = act(A[N,KT] @ W[KT,128](ldw) + bias
//                                    + bias2[gidx[n]])
// Optional fused attention scores: outS/outD[n][head] = sum_c out[n][c]*att[c]
// ---------------------------------------------------------------------------
__device__ __forceinline__ void fma_rank1(float acc[8][4], float4 aL, float4 aH, float4 w)
{
    float ar[8] = {aL.x, aL.y, aL.z, aL.w, aH.x, aH.y, aH.z, aH.w};
    float wr[4] = {w.x, w.y, w.z, w.w};
#pragma unroll
    for (int r = 0; r < 8; r++)
#pragma unroll
        for (int j = 0; j < 4; j++) acc[r][j] += ar[r] * wr[j];
}

template<int KT>
__global__ __launch_bounds__(256) void gemm128(
    const float* __restrict__ A, const float* __restrict__ W,
    const float* __restrict__ bias, const float* __restrict__ bias2,
    const int* __restrict__ gidx, float* __restrict__ out,
    int Nrows, int ldw, int act,
    const float* __restrict__ attS, const float* __restrict__ attD,
    float* __restrict__ outS, float* __restrict__ outD)
{
    __shared__ float As[KT * 68];
    const int tid = threadIdx.x;
    const int rowBase = blockIdx.x * 64;

    for (int idx = tid; idx < 64 * KT; idx += 256) {
        int row = idx / KT;
        int k = idx - row * KT;
        int n = rowBase + row;
        As[k * 68 + row] = (n < Nrows) ? A[(size_t)n * KT + k] : 0.f;
    }
    __syncthreads();

    const int c0 = (tid & 31) * 4;
    const int n0 = (tid >> 5) * 8;

    float acc[8][4];
#pragma unroll
    for (int r = 0; r < 8; r++)
#pragma unroll
        for (int j = 0; j < 4; j++) acc[r][j] = 0.f;

    const float* wp = W + c0;
    int k = 0;
    for (; k + 4 <= KT; k += 4) {
        float4 w0 = *(const float4*)&wp[(size_t)(k + 0) * ldw];
        float4 w1 = *(const float4*)&wp[(size_t)(k + 1) * ldw];
        float4 w2 = *(const float4*)&wp[(size_t)(k + 2) * ldw];
        float4 w3 = *(const float4*)&wp[(size_t)(k + 3) * ldw];
        float4 aL0 = *(const float4*)&As[(k + 0) * 68 + n0];
        float4 aH0 = *(const float4*)&As[(k + 0) * 68 + n0 + 4];
        float4 aL1 = *(const float4*)&As[(k + 1) * 68 + n0];
        float4 aH1 = *(const float4*)&As[(k + 1) * 68 + n0 + 4];
        float4 aL2 = *(const float4*)&As[(k + 2) * 68 + n0];
        float4 aH2 = *(const float4*)&As[(k + 2) * 68 + n0 + 4];
        float4 aL3 = *(const float4*)&As[(k + 3) * 68 + n0];
        float4 aH3 = *(const float4*)&As[(k + 3) * 68 + n0 + 4];
        fma_rank1(acc, aL0, aH0, w0);
        fma_rank1(acc, aL1, aH1, w1);
        fma_rank1(acc, aL2, aH2, w2);
        fma_rank1(acc, aL3, aH3, w3);
    }
    for (; k < KT; ++k) {
        float4 w0 = *(const float4*)&wp[(size_t)k * ldw];
        float4 aL = *(const float4*)&As[k * 68 + n0];
        float4 aH = *(const float4*)&As[k * 68 + n0 + 4];
        fma_rank1(acc, aL, aH, w0);
    }

    float4 bv = make_float4(0.f, 0.f, 0.f, 0.f);
    if (bias) bv = *(const float4*)&bias[c0];
    float4 aSv = make_float4(0.f, 0.f, 0.f, 0.f);
    float4 aDv = make_float4(0.f, 0.f, 0.f, 0.f);
    if (outS) { aSv = *(const float4*)&attS[c0]; aDv = *(const float4*)&attD[c0]; }

#pragma unroll
    for (int r = 0; r < 8; r++) {
        int n = rowBase + n0 + r;
        if (n >= Nrows) break;   // uniform within each 32-lane group
        float4 o;
        o.x = acc[r][0] + bv.x;
        o.y = acc[r][1] + bv.y;
        o.z = acc[r][2] + bv.z;
        o.w = acc[r][3] + bv.w;
        if (bias2) {
            float4 b2 = *(const float4*)&bias2[(size_t)gidx[n] * H + c0];
            o.x += b2.x; o.y += b2.y; o.z += b2.z; o.w += b2.w;
        }
        if (act) {
            o.x = silu_f(o.x); o.y = silu_f(o.y);
            o.z = silu_f(o.z); o.w = silu_f(o.w);
        }
        *(float4*)&out[(size_t)n * H + c0] = o;
        if (outS) {
            float ps = o.x * aSv.x + o.y * aSv.y + o.z * aSv.z + o.w * aSv.w;
            float pd = o.x * aDv.x + o.y * aDv.y + o.z * aDv.z + o.w * aDv.w;
#pragma unroll
            for (int off = 4; off >= 1; off >>= 1) {
                ps += __shfl_xor(ps, off, 8);
                pd += __shfl_xor(pd, off, 8);
            }
            if ((tid & 7) == 0) {
                int head = (tid & 31) >> 3;
                outS[n * 4 + head] = ps;
                outD[n * 4 + head] = pd;
            }
        }
    }
}

// ---------------------------------------------------------------------------
// Final GEMM: out[N,39] = A[N,128] @ W[128,39] + bias.
// ---------------------------------------------------------------------------
__global__ __launch_bounds__(256) void gemm_out39(
    const float* __restrict__ A, const float* __restrict__ W,
    const float* __restrict__ bias, float* __restrict__ out, int Nrows)
{
    const int K = 128, OC = AD, NPB = 100, NCG = 10, APAD = 104;
    __shared__ float A_lds[K * APAD];
    const int tid = threadIdx.x;
    const int rowBase = blockIdx.x * NPB;

    for (int idx = tid; idx < NPB * K; idx += 256) {
        int node = idx >> 7;
        int k = idx & 127;
        int n = rowBase + node;
        A_lds[k * APAD + node] = (n < Nrows) ? A[(size_t)n * K + k] : 0.f;
    }
    __syncthreads();

    const int cg = tid % NCG;
    const int ng = tid / NCG;
    const int c0 = cg * 4, n0 = ng * 4;
    if (n0 >= NPB) return;

    float acc[16];
#pragma unroll
    for (int i = 0; i < 16; i++) acc[i] = 0.f;

#pragma unroll 4
    for (int k = 0; k < K; k++) {
        float4 a = *(const float4*)&A_lds[k * APAD + n0];
        size_t base = (size_t)k * OC + c0;
        float w0 = W[base + 0];
        float w1 = (c0 + 1 < OC) ? W[base + 1] : 0.f;
        float w2 = (c0 + 2 < OC) ? W[base + 2] : 0.f;
        float w3 = (c0 + 3 < OC) ? W[base + 3] : 0.f;
        acc[0]  += a.x * w0; acc[1]  += a.x * w1; acc[2]  += a.x * w2; acc[3]  += a.x * w3;
        acc[4]  += a.y * w0; acc[5]  += a.y * w1; acc[6]  += a.y * w2; acc[7]  += a.y * w3;
        acc[8]  += a.z * w0; acc[9]  += a.z * w1; acc[10] += a.z * w2; acc[11] += a.z * w3;
        acc[12] += a.w * w0; acc[13] += a.w * w1; acc[14] += a.w * w2; acc[15] += a.w * w3;
    }

#pragma unroll
    for (int i = 0; i < 4; i++) {
        int n = rowBase + n0 + i;
        if (n >= Nrows) continue;
#pragma unroll
        for (int j = 0; j < 4; j++) {
            int c = c0 + j;
            if (c >= OC) continue;
            out[(size_t)n * OC + c] = acc[i * 4 + j] + bias[c];
        }
    }
}

// ---------------------------------------------------------------------------
// Fold edge path coefficients
// ---------------------------------------------------------------------------
__global__ __launch_bounds__(256) void precompute_small(
    const float* __restrict__ edge_W, const float* __restrict__ att_edge,
    const float* __restrict__ bond_W, const float* __restrict__ bond_b,
    float* __restrict__ mc)
{
    __shared__ float bl[LAYERS][H][4];
    int tid = threadIdx.x;
    for (int task = tid; task < LAYERS * H; task += 256) {
        int l = task / H, k = task % H;
#pragma unroll
        for (int hh = 0; hh < 4; hh++) {
            float s = 0.f;
            for (int d = 0; d < HD; d++)
                s += edge_W[(size_t)l * H * H + k * H + hh * HD + d] *
                     att_edge[l * H + hh * HD + d];
            bl[l][k][hh] = s;
        }
    }
    __syncthreads();
    if (tid < LAYERS * BD * 4) {
        int l = tid / (BD * 4), r = tid % (BD * 4), j = r / 4, hh = r % 4;
        float s = 0.f;
        for (int k = 0; k < H; k++) s += bond_W[j * H + k] * bl[l][k][hh];
        mc[l * 44 + j * 4 + hh] = s;
    }
    if (tid >= 128 && tid < 128 + LAYERS * 4) {
        int r = tid - 128, l = r / 4, hh = r % 4;
        float s = 0.f;
        for (int k = 0; k < H; k++) s += bond_b[k] * bl[l][k][hh];
        mc[l * 44 + 40 + hh] = s;
    }
}

// ---------------------------------------------------------------------------
__global__ __launch_bounds__(128) void time_embed(
    const int* __restrict__ t,
    const float* __restrict__ W1, const float* __restrict__ b1,
    const float* __restrict__ W2, const float* __restrict__ b2,
    float* __restrict__ t_emb)
{
    int g = blockIdx.x, c = threadIdx.x;
    float tf = (float)t[g];
    __shared__ float emb[TD], z[H];
    int k = c & 63;
    float f = __expf(-9.210340371976184f * (float)k / 63.0f);
    float e = tf * f;
    emb[c] = (c < 64) ? sinf(e) : cosf(e);
    __syncthreads();
    float a1 = b1[c];
    for (int kk = 0; kk < TD; kk++) a1 += emb[kk] * W1[kk * H + c];
    z[c] = silu_f(a1);
    __syncthreads();
    float a2 = b2[c];
    for (int kk = 0; kk < H; kk++) a2 += z[kk] * W2[kk * H + c];
    t_emb[g * H + c] = a2;
}

// ---------------------------------------------------------------------------
// CSR build
// ---------------------------------------------------------------------------
__global__ __launch_bounds__(256) void hist_dst(const int* __restrict__ edge_index,
                                                int* __restrict__ deg)
{
    int e = blockIdx.x * 256 + threadIdx.x;
    if (e < N_EDGES) atomicAdd(&deg[edge_index[N_EDGES + e]], 1);
}

// batch is sorted: gptr[g] = lower_bound(batch, g)
__global__ __launch_bounds__(320) void gptr_bsearch(const int* __restrict__ batch,
                                                    int* __restrict__ gptr)
{
    int g = threadIdx.x;
    if (g > NB) return;
    int lo = 0, hi = N_NODES;
    while (lo < hi) {
        int mid = (lo + hi) >> 1;
        if (batch[mid] < g) lo = mid + 1; else hi = mid;
    }
    gptr[g] = lo;
}

__global__ __launch_bounds__(256) void scan_part(const int* __restrict__ cnt,
                                                 int* __restrict__ bsum, int n)
{
    int tid = threadIdx.x;
    int i0 = blockIdx.x * 1024 + tid * 4;
    int s = 0;
#pragma unroll
    for (int j = 0; j < 4; j++) if (i0 + j < n) s += cnt[i0 + j];
    __shared__ int red[256];
    red[tid] = s;
    __syncthreads();
    for (int off = 128; off >= 1; off >>= 1) {
        if (tid < off) red[tid] += red[tid + off];
        __syncthreads();
    }
    if (tid == 0) bsum[blockIdx.x] = red[0];
}

__global__ __launch_bounds__(256) void scan_tops(const int* __restrict__ bsum,
                                                 int* __restrict__ boff, int G,
                                                 int* __restrict__ total)
{
    int tid = threadIdx.x;
    int v = (tid < G) ? bsum[tid] : 0;
    __shared__ int ps[256];
    ps[tid] = v;
    __syncthreads();
    for (int off = 1; off < 256; off <<= 1) {
        int t = (tid >= off) ? ps[tid - off] : 0;
        __syncthreads();
        ps[tid] += t;
        __syncthreads();
    }
    if (tid < G) boff[tid] = ps[tid] - v;
    if (tid == 255) *total = ps[255];
}

__global__ __launch_bounds__(256) void scan_final(const int* __restrict__ cnt,
                                                  const int* __restrict__ boff,
                                                  int* __restrict__ ptr, int n)
{
    int tid = threadIdx.x;
    int i0 = blockIdx.x * 1024 + tid * 4;
    int v[4];
#pragma unroll
    for (int j = 0; j < 4; j++) v[j] = (i0 + j < n) ? cnt[i0 + j] : 0;
    int s = v[0] + v[1] + v[2] + v[3];
    __shared__ int ps[256];
    ps[tid] = s;
    __syncthreads();
    for (int off = 1; off < 256; off <<= 1) {
        int t = (tid >= off) ? ps[tid - off] : 0;
        __syncthreads();
        ps[tid] += t;
        __syncthreads();
    }
    int run = boff[blockIdx.x] + ps[tid] - s;
#pragma unroll
    for (int j = 0; j < 4; j++) {
        if (i0 + j < n) { ptr[i0 + j] = run; run += v[j]; }
    }
}

__global__ __launch_bounds__(256) void scatter_edges(const int* __restrict__ edge_index,
                                                     const int* __restrict__ ptr,
                                                     int* __restrict__ cursor,
                                                     int* __restrict__ src_csr,
                                                     int* __restrict__ rank)
{
    int e = blockIdx.x * 256 + threadIdx.x;
    if (e >= N_EDGES) return;
    int s = edge_index[e];
    int d = edge_index[N_EDGES + e];
    int pos = atomicAdd(&cursor[d], 1);
    int p = ptr[d] + pos;
    src_csr[p] = s;
    rank[e] = p;
}

// ---------------------------------------------------------------------------
// Per-edge scores, ALL 4 heads, written in CSR order as half4 via rank[e].
// ---------------------------------------------------------------------------
__global__ __launch_bounds__(256) void edge_scores_4h(
    const float* __restrict__ edge_attr, const int* __restrict__ edge_index,
    const int* __restrict__ rank, const float* __restrict__ mc_l,
    const float* __restrict__ sS, const float* __restrict__ sD,
    __half* __restrict__ alpha)
{
    __shared__ float Ml[BD * 4], cl[4];
    int tid = threadIdx.x;
    if (tid < 40) Ml[tid] = mc_l[tid];
    if (tid >= 40 && tid < 44) cl[tid - 40] = mc_l[tid];
    __syncthreads();
    int e = blockIdx.x * 256 + tid;
    if (e >= N_EDGES) return;
    float se0 = cl[0], se1 = cl[1], se2 = cl[2], se3 = cl[3];
#pragma unroll
    for (int j = 0; j < BD; j++) {
        float x = edge_attr[(size_t)e * BD + j];
        se0 += x * Ml[j * 4 + 0]; se1 += x * Ml[j * 4 + 1];
        se2 += x * Ml[j * 4 + 2]; se3 += x * Ml[j * 4 + 3];
    }
    int s = edge_index[e];
    int d = edge_index[N_EDGES + e];
    float4 ss = *(const float4*)&sS[s * 4];
    float4 sd = *(const float4*)&sD[d * 4];
    float a0 = ss.x + sd.x + se0; a0 = (a0 >= 0.f) ? a0 : 0.2f * a0;
    float a1 = ss.y + sd.y + se1; a1 = (a1 >= 0.f) ? a1 : 0.2f * a1;
    float a2 = ss.z + sd.z + se2; a2 = (a2 >= 0.f) ? a2 : 0.2f * a2;
    float a3 = ss.w + sd.w + se3; a3 = (a3 >= 0.f) ? a3 : 0.2f * a3;
    __half2 h01 = __floats2half2_rn(a0, a1);
    __half2 h23 = __floats2half2_rn(a2, a3);
    uint2 u = make_uint2(*(const unsigned*)&h01, *(const unsigned*)&h23);
    int p = rank[e];
    *(uint2*)&alpha[(size_t)p * 4] = u;
}

// ---------------------------------------------------------------------------
// GAT aggregation for one half: one wave per dst node, online softmax.
// alpha (half[E][4]) and src_csr in CSR order -> coalesced streams.
// ---------------------------------------------------------------------------
__global__ __launch_bounds__(256) void gat_agg_h(
    const float* __restrict__ xh, int coff, const __half* __restrict__ alpha,
    int hh0, const int* __restrict__ csr_ptr, const int* __restrict__ src_csr,
    const float* __restrict__ conv_b_off, float* __restrict__ agg)
{
    int n = (blockIdx.x * 256 + threadIdx.x) >> 6;
    if (n >= N_NODES) return;
    int lane = threadIdx.x & 63;
    int c = coff + lane;
    int hoff = hh0 + (lane >> 5);
    int start = csr_ptr[n], end = csr_ptr[n + 1];

    float m_run = -1e30f, d_run = 0.f, acc = 0.f;

    for (int base = start; base < end; base += 64) {
        int cnt = min(64, end - base);
        int s_l = (lane < cnt) ? src_csr[base + lane] : 0;
        int i0 = lane & 31;
        float a0 = (i0 < cnt)      ? __half2float(alpha[(size_t)(base + i0) * 4 + hoff])      : -1e30f;
        float a1 = (i0 + 32 < cnt) ? __half2float(alpha[(size_t)(base + i0 + 32) * 4 + hoff]) : -1e30f;

        float m_blk = fmaxf(a0, a1);
#pragma unroll
        for (int off = 16; off >= 1; off >>= 1)
            m_blk = fmaxf(m_blk, __shfl_xor(m_blk, off, 32));
        float m_new = fmaxf(m_run, m_blk);
        float rescale = __expf(m_run - m_new);
        float e0 = __expf(a0 - m_new);
        float e1 = __expf(a1 - m_new);
        float dsum = e0 + e1;
#pragma unroll
        for (int off = 16; off >= 1; off >>= 1)
            dsum += __shfl_xor(dsum, off, 32);
        d_run = d_run * rescale + dsum;
        acc *= rescale;

        int c1 = min(cnt, 32);
        for (int i = 0; i < c1; i += 4) {
            int s0 = __shfl(s_l, i + 0), s1 = __shfl(s_l, i + 1);
            int s2 = __shfl(s_l, i + 2), s3 = __shfl(s_l, i + 3);
            float w0 = __shfl(e0, i + 0, 32), w1 = __shfl(e0, i + 1, 32);
            float w2 = __shfl(e0, i + 2, 32), w3 = __shfl(e0, i + 3, 32);
            float x0 = xh[(size_t)s0 * H + c];
            float x1 = xh[(size_t)s1 * H + c];
            float x2 = xh[(size_t)s2 * H + c];
            float x3 = xh[(size_t)s3 * H + c];
            acc += x0 * w0 + x1 * w1 + x2 * w2 + x3 * w3;
        }
        for (int i = 32; i < cnt; i += 4) {
            int s0 = __shfl(s_l, i + 0), s1 = __shfl(s_l, i + 1);
            int s2 = __shfl(s_l, i + 2), s3 = __shfl(s_l, i + 3);
            float w0 = __shfl(e1, i - 32, 32), w1 = __shfl(e1, i - 31, 32);
            float w2 = __shfl(e1, i - 30, 32), w3 = __shfl(e1, i - 29, 32);
            float x0 = xh[(size_t)s0 * H + c];
            float x1 = xh[(size_t)s1 * H + c];
            float x2 = xh[(size_t)s2 * H + c];
            float x3 = xh[(size_t)s3 * H + c];
            acc += x0 * w0 + x1 * w1 + x2 * w2 + x3 * w3;
        }
        m_run = m_new;
    }
    float inv = 1.f / (d_run + 1e-16f);
    agg[(size_t)n * HQ + lane] = acc * inv + conv_b_off[lane];
}

// ---------------------------------------------------------------------------
// BatchNorm (per half, 64 channels)
// ---------------------------------------------------------------------------
__global__ __launch_bounds__(256) void bn_partial_h(const float* __restrict__ agg,
                                                    float* __restrict__ part)
{
    __shared__ float red[2][4][64];
    int b = blockIdx.x;
    int c = threadIdx.x & 63;
    int q = threadIdx.x >> 6;
    int per = (N_NODES + 255) / 256;
    int s = b * per, e = min(N_NODES, s + per);
    int qs = s + q * ((per + 3) / 4);
    int qe = min(e, qs + (per + 3) / 4);
    float sum = 0.f, sq = 0.f;
    for (int n = qs; n < qe; n++) {
        float v = agg[(size_t)n * HQ + c];
        sum += v; sq += v * v;
    }
    red[0][q][c] = sum;
    red[1][q][c] = sq;
    __syncthreads();
    if (q == 0) {
        sum = red[0][0][c] + red[0][1][c] + red[0][2][c] + red[0][3][c];
        sq  = red[1][0][c] + red[1][1][c] + red[1][2][c] + red[1][3][c];
        part[b * HQ + c] = sum;
        part[256 * HQ + b * HQ + c] = sq;
    }
}

__global__ __launch_bounds__(256) void bn_finish_h(const float* __restrict__ part,
                                                   const float* __restrict__ gamma,
                                                   const float* __restrict__ beta,
                                                   float* __restrict__ scale,
                                                   float* __restrict__ shift)
{
    __shared__ double red[2][4][64];
    int c = threadIdx.x & 63;
    int g = threadIdx.x >> 6;
    double s = 0.0, q = 0.0;
    for (int b = g * 64; b < (g + 1) * 64; b++) {
        s += (double)part[b * HQ + c];
        q += (double)part[256 * HQ + b * HQ + c];
    }
    red[0][g][c] = s;
    red[1][g][c] = q;
    __syncthreads();
    if (g == 0) {
        s = red[0][0][c] + red[0][1][c] + red[0][2][c] + red[0][3][c];
        q = red[1][0][c] + red[1][1][c] + red[1][2][c] + red[1][3][c];
        float mu = (float)(s / N_NODES);
        float var = (float)(q / N_NODES) - mu * mu;
        float rstd = rsqrtf(var + 1e-5f);
        float sc = gamma[c] * rstd;
        scale[c] = sc;
        shift[c] = beta[c] - mu * sc;
    }
}

__global__ __launch_bounds__(256) void bn_apply_h(const float* __restrict__ agg,
                                                  const float* __restrict__ scale,
                                                  const float* __restrict__ shift,
                                                  float* __restrict__ h, int coff)
{
    int i = blockIdx.x * 256 + threadIdx.x;
    if (i >= N_NODES * HQ / 4) return;
    int n = i >> 4;
    int c0 = (i & 15) * 4;
    float4 v = *(const float4*)&agg[(size_t)n * HQ + c0];
    float4 sc = *(const float4*)&scale[c0];
    float4 sh = *(const float4*)&shift[c0];
    float* hp = &h[(size_t)n * H + coff + c0];
    float4 hv = *(const float4*)hp;
    float4 o;
    o.x = fmaxf(v.x * sc.x + sh.x, 0.f) + hv.x;
    o.y = fmaxf(v.y * sc.y + sh.y, 0.f) + hv.y;
    o.z = fmaxf(v.z * sc.z + sh.z, 0.f) + hv.z;
    o.w = fmaxf(v.w * sc.w + sh.w, 0.f) + hv.w;
    *(float4*)hp = o;
}

// ---------------------------------------------------------------------------
// Graph head
// ---------------------------------------------------------------------------
__global__ __launch_bounds__(128) void graph_head(
    const float* __restrict__ nf, const int* __restrict__ gptr,
    const float* __restrict__ t_emb,
    const float* __restrict__ pW1, const float* __restrict__ pb1,
    const float* __restrict__ pW2, const float* __restrict__ pb2,
    const float* __restrict__ npW1, const float* __restrict__ npb1,
    float* __restrict__ tgW)
{
    int g = blockIdx.x, c = threadIdx.x;
    int s = gptr[g], e = gptr[g + 1];
    float sum = 0.f;
    for (int n = s; n < e; n++) sum += nf[(size_t)n * H + c];
    float cf = (e - s > 0) ? (float)(e - s) : 1.f;
    __shared__ float row[H], z[H];
    row[c] = sum / cf;
    __syncthreads();
    float a1 = pb1[c];
    for (int k = 0; k < H; k++) a1 += row[k] * pW1[k * H + c];
    z[c] = silu_f(a1);
    __syncthreads();
    float a2 = pb2[c];
    for (int k = 0; k < H; k++) a2 += z[k] * pW2[k * H + c];
    float tg = a2 + t_emb[g * H + c];
    __syncthreads();
    row[c] = tg;
    __syncthreads();
    float a3 = npb1[c];
    for (int k = 0; k < H; k++) a3 += row[k] * npW1[(size_t)(128 + k) * H + c];
    tgW[g * H + c] = a3;
}

// ---------------------------------------------------------------------------
extern "C" void kernel_launch(void* const* d_in, const int* in_sizes, int n_in,
                              void* d_out, int out_size, void* d_ws, size_t ws_size,
                              hipStream_t stream)
{
    const float* x          = (const float*)d_in[0];
    const int*   edge_index = (const int*)d_in[1];
    const float* edge_attr  = (const float*)d_in[2];
    const int*   batch      = (const int*)d_in[3];
    const int*   t          = (const int*)d_in[4];
    const float* atom_W     = (const float*)d_in[5];
    const float* atom_b     = (const float*)d_in[6];
    const float* bond_W     = (const float*)d_in[7];
    const float* bond_b     = (const float*)d_in[8];
    const float* lin_W      = (const float*)d_in[9];
    const float* edge_W     = (const float*)d_in[10];
    const float* att_src    = (const float*)d_in[11];
    const float* att_dst    = (const float*)d_in[12];
    const float* att_edge   = (const float*)d_in[13];
    const float* conv_b     = (const float*)d_in[14];
    const float* bn_gamma   = (const float*)d_in[15];
    const float* bn_beta    = (const float*)d_in[16];
    const float* out_W      = (const float*)d_in[17];
    const float* out_b      = (const float*)d_in[18];
    const float* time_W1    = (const float*)d_in[19];
    const float* time_b1    = (const float*)d_in[20];
    const float* time_W2    = (const float*)d_in[21];
    const float* time_b2    = (const float*)d_in[22];
    const float* pool_W1    = (const float*)d_in[23];
    const float* pool_b1    = (const float*)d_in[24];
    const float* pool_W2    = (const float*)d_in[25];
    const float* pool_b2    = (const float*)d_in[26];
    const float* np_W1      = (const float*)d_in[27];
    const float* np_b1      = (const float*)d_in[28];
    const float* np_W2      = (const float*)d_in[29];
    const float* np_b2      = (const float*)d_in[30];
    const float* np_W3      = (const float*)d_in[31];
    const float* np_b3      = (const float*)d_in[32];

    // ---------------- workspace layout (floats), total 71.6 MB ----------------
    const size_t OFF_H     = 0;                      // [N*H]
    const size_t OFF_XH    = 6400000;                // [N*H]
    const size_t OFF_AGG   = 12800000;               // [N*HQ]
    const size_t OFF_ALPHA = 16000000;               // half[E][4] = 1.6M floats
    const size_t OFF_SD    = 17600000;               // [N*4]
    const size_t OFF_TEMB  = 17800000;               // [NB*H]
    const size_t OFF_TGW   = 17832768;               // [NB*H]
    const size_t OFF_MC    = 17865536;               // 256
    const size_t OFF_BNSC  = 17865792;               // 128
    const size_t OFF_BNSH  = 17865920;               // 128
    const size_t OFF_PART  = 17866048;               // 32768
    const size_t REQ_FLOATS = 17898816;
    const size_t REQ_BYTES  = REQ_FLOATS * 4;        // 71,595,264 (proven OK)

    if (ws_size < REQ_BYTES) {
        hipMemsetAsync(d_out, 0, (size_t)out_size * sizeof(float), stream);
        return;
    }

    float* fws    = (float*)d_ws;
    float* h      = fws + OFF_H;
    float* xh     = fws + OFF_XH;
    float* agg    = fws + OFF_AGG;
    __half* alpha = (__half*)(fws + OFF_ALPHA);
    float* sD     = fws + OFF_SD;
    float* t_emb  = fws + OFF_TEMB;
    float* tgW    = fws + OFF_TGW;
    float* mc     = fws + OFF_MC;
    float* bnsc   = fws + OFF_BNSC;
    float* bnsh   = fws + OFF_BNSH;
    float* part   = fws + OFF_PART;

    // d_out scratch (1,950,000 floats): CSR ints + rank + sS.
    int* ib       = (int*)d_out;
    int* csr_ptr  = ib;                    // 50,016
    int* src_csr  = ib + 50016;            // 800,000
    int* rank     = ib + 850016;           // 800,000
    int* deg      = ib + 1650016;          // 50,016 (hist + scatter cursor)
    int* gptr     = ib + 1700032;          // 260
    int* bsum     = ib + 1700292;          // 64
    int* boff     = ib + 1700356;          // 64
    float* sS     = (float*)d_out + 1700420;  // [N*4] (end 1,900,420)

    hipMemsetAsync(deg, 0, N_NODES * sizeof(int), stream);

    precompute_small<<<1, 256, 0, stream>>>(edge_W, att_edge, bond_W, bond_b, mc);
    time_embed<<<NB, 128, 0, stream>>>(t, time_W1, time_b1, time_W2, time_b2, t_emb);
    gptr_bsearch<<<1, 320, 0, stream>>>(batch, gptr);

    hist_dst<<<(N_EDGES + 255) / 256, 256, 0, stream>>>(edge_index, deg);

    const int GSN = (N_NODES + 1023) / 1024;  // 49
    scan_part<<<GSN, 256, 0, stream>>>(deg, bsum, N_NODES);
    scan_tops<<<1, 256, 0, stream>>>(bsum, boff, GSN, &csr_ptr[N_NODES]);
    scan_final<<<GSN, 256, 0, stream>>>(deg, boff, csr_ptr, N_NODES);

    hipMemsetAsync(deg, 0, N_NODES * sizeof(int), stream);
    scatter_edges<<<(N_EDGES + 255) / 256, 256, 0, stream>>>(edge_index, csr_ptr,
                                                             deg, src_csr, rank);

    const int GB = (N_NODES + 63) / 64;

    // h = x @ atom_W + atom_b
    gemm128<AD><<<GB, 256, 0, stream>>>(x, atom_W, atom_b, nullptr, nullptr,
                                        h, N_NODES, H, 0,
                                        nullptr, nullptr, nullptr, nullptr);

    for (int l = 0; l < LAYERS; l++) {
        // xh = h @ lin_W[l], fused attention scores sS/sD
        gemm128<H><<<GB, 256, 0, stream>>>(h, lin_W + (size_t)l * H * H, nullptr,
                                           nullptr, nullptr, xh, N_NODES, H, 0,
                                           att_src + l * H, att_dst + l * H, sS, sD);
        edge_scores_4h<<<(N_EDGES + 255) / 256, 256, 0, stream>>>(
            edge_attr, edge_index, rank, mc + l * 44, sS, sD, alpha);
        for (int half = 0; half < 2; half++) {
            int hh0 = half * 2;
            int coff = half * HQ;
            gat_agg_h<<<N_NODES / 4, 256, 0, stream>>>(
                xh, coff, alpha, hh0, csr_ptr, src_csr, conv_b + l * H + coff, agg);
            bn_partial_h<<<256, 256, 0, stream>>>(agg, part);
            bn_finish_h<<<1, 256, 0, stream>>>(part, bn_gamma + l * H + coff,
                                               bn_beta + l * H + coff, bnsc, bnsh);
            bn_apply_h<<<(N_NODES * HQ / 4 + 255) / 256, 256, 0, stream>>>(
                agg, bnsc, bnsh, h, coff);
        }
    }

    // node_features = h @ out_W + out_b  -> xh
    gemm128<H><<<GB, 256, 0, stream>>>(h, out_W, out_b, nullptr, nullptr,
                                       xh, N_NODES, H, 0,
                                       nullptr, nullptr, nullptr, nullptr);

    graph_head<<<NB, 128, 0, stream>>>(xh, gptr, t_emb, pool_W1, pool_b1,
                                       pool_W2, pool_b2, np_W1, np_b1, tgW);

    // z1 = silu(nf @ np_W1[0:128] + tgW[batch]) -> h
    gemm128<H><<<GB, 256, 0, stream>>>(xh, np_W1, nullptr, tgW, batch,
                                       h, N_NODES, H, 1,
                                       nullptr, nullptr, nullptr, nullptr);
    // z2 = silu(z1 @ np_W2 + np_b2) -> xh
    gemm128<H><<<GB, 256, 0, stream>>>(h, np_W2, np_b2, nullptr, nullptr,
                                       xh, N_NODES, H, 1,
                                       nullptr, nullptr, nullptr, nullptr);
    // out = z2 @ np_W3 + np_b3 -> d_out [N,39]
    gemm_out39<<<(N_NODES + 99) / 100, 256, 0, stream>>>(xh, np_W3, np_b3,
                                                         (float*)d_out, N_NODES);
}

// Round 8
// 941.297 us; speedup vs baseline: 2.1232x; 1.0402x over previous
//
#include <hip/hip_runtime.h>
#include <hip/hip_fp16.h>
#include <math.h>

#define N_NODES 50000
#define N_EDGES 800000
#define NB 256
#define AD 39
#define BD 10
#define H 128
#define HQ 64
#define HEADS 4
#define HD 32
#define LAYERS 3
#define TD 128

__device__ __forceinline__ float silu_f(float x) { return x / (1.f + __expf(-x)); }

// ---------------------------------------------------------------------------
// Specialized GEMM: out[N,128] = act(A[N,KT] @ W[KT,128](ldw) + bias
//                                    + bias2[gidx[n]])
// Optional fused attention scores: outS/outD[n][head] = sum_c out[n][c]*att[c]
// ---------------------------------------------------------------------------
__device__ __forceinline__ void fma_rank1(float acc[8][4], float4 aL, float4 aH, float4 w)
{
    float ar[8] = {aL.x, aL.y, aL.z, aL.w, aH.x, aH.y, aH.z, aH.w};
    float wr[4] = {w.x, w.y, w.z, w.w};
#pragma unroll
    for (int r = 0; r < 8; r++)
#pragma unroll
        for (int j = 0; j < 4; j++) acc[r][j] += ar[r] * wr[j];
}

template<int KT>
__global__ __launch_bounds__(256) void gemm128(
    const float* __restrict__ A, const float* __restrict__ W,
    const float* __restrict__ bias, const float* __restrict__ bias2,
    const int* __restrict__ gidx, float* __restrict__ out,
    int Nrows, int ldw, int act,
    const float* __restrict__ attS, const float* __restrict__ attD,
    float* __restrict__ outS, float* __restrict__ outD)
{
    __shared__ float As[KT * 68];
    const int tid = threadIdx.x;
    const int rowBase = blockIdx.x * 64;

    for (int idx = tid; idx < 64 * KT; idx += 256) {
        int row = idx / KT;
        int k = idx - row * KT;
        int n = rowBase + row;
        As[k * 68 + row] = (n < Nrows) ? A[(size_t)n * KT + k] : 0.f;
    }
    __syncthreads();

    const int c0 = (tid & 31) * 4;
    const int n0 = (tid >> 5) * 8;

    float acc[8][4];
#pragma unroll
    for (int r = 0; r < 8; r++)
#pragma unroll
        for (int j = 0; j < 4; j++) acc[r][j] = 0.f;

    const float* wp = W + c0;
    int k = 0;
    for (; k + 4 <= KT; k += 4) {
        float4 w0 = *(const float4*)&wp[(size_t)(k + 0) * ldw];
        float4 w1 = *(const float4*)&wp[(size_t)(k + 1) * ldw];
        float4 w2 = *(const float4*)&wp[(size_t)(k + 2) * ldw];
        float4 w3 = *(const float4*)&wp[(size_t)(k + 3) * ldw];
        float4 aL0 = *(const float4*)&As[(k + 0) * 68 + n0];
        float4 aH0 = *(const float4*)&As[(k + 0) * 68 + n0 + 4];
        float4 aL1 = *(const float4*)&As[(k + 1) * 68 + n0];
        float4 aH1 = *(const float4*)&As[(k + 1) * 68 + n0 + 4];
        float4 aL2 = *(const float4*)&As[(k + 2) * 68 + n0];
        float4 aH2 = *(const float4*)&As[(k + 2) * 68 + n0 + 4];
        float4 aL3 = *(const float4*)&As[(k + 3) * 68 + n0];
        float4 aH3 = *(const float4*)&As[(k + 3) * 68 + n0 + 4];
        fma_rank1(acc, aL0, aH0, w0);
        fma_rank1(acc, aL1, aH1, w1);
        fma_rank1(acc, aL2, aH2, w2);
        fma_rank1(acc, aL3, aH3, w3);
    }
    for (; k < KT; ++k) {
        float4 w0 = *(const float4*)&wp[(size_t)k * ldw];
        float4 aL = *(const float4*)&As[k * 68 + n0];
        float4 aH = *(const float4*)&As[k * 68 + n0 + 4];
        fma_rank1(acc, aL, aH, w0);
    }

    float4 bv = make_float4(0.f, 0.f, 0.f, 0.f);
    if (bias) bv = *(const float4*)&bias[c0];
    float4 aSv = make_float4(0.f, 0.f, 0.f, 0.f);
    float4 aDv = make_float4(0.f, 0.f, 0.f, 0.f);
    if (outS) { aSv = *(const float4*)&attS[c0]; aDv = *(const float4*)&attD[c0]; }

#pragma unroll
    for (int r = 0; r < 8; r++) {
        int n = rowBase + n0 + r;
        if (n >= Nrows) break;   // uniform within each 32-lane group
        float4 o;
        o.x = acc[r][0] + bv.x;
        o.y = acc[r][1] + bv.y;
        o.z = acc[r][2] + bv.z;
        o.w = acc[r][3] + bv.w;
        if (bias2) {
            float4 b2 = *(const float4*)&bias2[(size_t)gidx[n] * H + c0];
            o.x += b2.x; o.y += b2.y; o.z += b2.z; o.w += b2.w;
        }
        if (act) {
            o.x = silu_f(o.x); o.y = silu_f(o.y);
            o.z = silu_f(o.z); o.w = silu_f(o.w);
        }
        *(float4*)&out[(size_t)n * H + c0] = o;
        if (outS) {
            float ps = o.x * aSv.x + o.y * aSv.y + o.z * aSv.z + o.w * aSv.w;
            float pd = o.x * aDv.x + o.y * aDv.y + o.z * aDv.z + o.w * aDv.w;
#pragma unroll
            for (int off = 4; off >= 1; off >>= 1) {
                ps += __shfl_xor(ps, off, 8);
                pd += __shfl_xor(pd, off, 8);
            }
            if ((tid & 7) == 0) {
                int head = (tid & 31) >> 3;
                outS[n * 4 + head] = ps;
                outD[n * 4 + head] = pd;
            }
        }
    }
}

// ---------------------------------------------------------------------------
// Final GEMM: out[N,39] = A[N,128] @ W[128,39] + bias.
// ---------------------------------------------------------------------------
__global__ __launch_bounds__(256) void gemm_out39(
    const float* __restrict__ A, const float* __restrict__ W,
    const float* __restrict__ bias, float* __restrict__ out, int Nrows)
{
    const int K = 128, OC = AD, NPB = 100, NCG = 10, APAD = 104;
    __shared__ float A_lds[K * APAD];
    const int tid = threadIdx.x;
    const int rowBase = blockIdx.x * NPB;

    for (int idx = tid; idx < NPB * K; idx += 256) {
        int node = idx >> 7;
        int k = idx & 127;
        int n = rowBase + node;
        A_lds[k * APAD + node] = (n < Nrows) ? A[(size_t)n * K + k] : 0.f;
    }
    __syncthreads();

    const int cg = tid % NCG;
    const int ng = tid / NCG;
    const int c0 = cg * 4, n0 = ng * 4;
    if (n0 >= NPB) return;

    float acc[16];
#pragma unroll
    for (int i = 0; i < 16; i++) acc[i] = 0.f;

#pragma unroll 4
    for (int k = 0; k < K; k++) {
        float4 a = *(const float4*)&A_lds[k * APAD + n0];
        size_t base = (size_t)k * OC + c0;
        float w0 = W[base + 0];
        float w1 = (c0 + 1 < OC) ? W[base + 1] : 0.f;
        float w2 = (c0 + 2 < OC) ? W[base + 2] : 0.f;
        float w3 = (c0 + 3 < OC) ? W[base + 3] : 0.f;
        acc[0]  += a.x * w0; acc[1]  += a.x * w1; acc[2]  += a.x * w2; acc[3]  += a.x * w3;
        acc[4]  += a.y * w0; acc[5]  += a.y * w1; acc[6]  += a.y * w2; acc[7]  += a.y * w3;
        acc[8]  += a.z * w0; acc[9]  += a.z * w1; acc[10] += a.z * w2; acc[11] += a.z * w3;
        acc[12] += a.w * w0; acc[13] += a.w * w1; acc[14] += a.w * w2; acc[15] += a.w * w3;
    }

#pragma unroll
    for (int i = 0; i < 4; i++) {
        int n = rowBase + n0 + i;
        if (n >= Nrows) continue;
#pragma unroll
        for (int j = 0; j < 4; j++) {
            int c = c0 + j;
            if (c >= OC) continue;
            out[(size_t)n * OC + c] = acc[i * 4 + j] + bias[c];
        }
    }
}

// ---------------------------------------------------------------------------
// Fold edge path coefficients
// ---------------------------------------------------------------------------
__global__ __launch_bounds__(256) void precompute_small(
    const float* __restrict__ edge_W, const float* __restrict__ att_edge,
    const float* __restrict__ bond_W, const float* __restrict__ bond_b,
    float* __restrict__ mc)
{
    __shared__ float bl[LAYERS][H][4];
    int tid = threadIdx.x;
    for (int task = tid; task < LAYERS * H; task += 256) {
        int l = task / H, k = task % H;
#pragma unroll
        for (int hh = 0; hh < 4; hh++) {
            float s = 0.f;
            for (int d = 0; d < HD; d++)
                s += edge_W[(size_t)l * H * H + k * H + hh * HD + d] *
                     att_edge[l * H + hh * HD + d];
            bl[l][k][hh] = s;
        }
    }
    __syncthreads();
    if (tid < LAYERS * BD * 4) {
        int l = tid / (BD * 4), r = tid % (BD * 4), j = r / 4, hh = r % 4;
        float s = 0.f;
        for (int k = 0; k < H; k++) s += bond_W[j * H + k] * bl[l][k][hh];
        mc[l * 44 + j * 4 + hh] = s;
    }
    if (tid >= 128 && tid < 128 + LAYERS * 4) {
        int r = tid - 128, l = r / 4, hh = r % 4;
        float s = 0.f;
        for (int k = 0; k < H; k++) s += bond_b[k] * bl[l][k][hh];
        mc[l * 44 + 40 + hh] = s;
    }
}

// ---------------------------------------------------------------------------
__global__ __launch_bounds__(128) void time_embed(
    const int* __restrict__ t,
    const float* __restrict__ W1, const float* __restrict__ b1,
    const float* __restrict__ W2, const float* __restrict__ b2,
    float* __restrict__ t_emb)
{
    int g = blockIdx.x, c = threadIdx.x;
    float tf = (float)t[g];
    __shared__ float emb[TD], z[H];
    int k = c & 63;
    float f = __expf(-9.210340371976184f * (float)k / 63.0f);
    float e = tf * f;
    emb[c] = (c < 64) ? sinf(e) : cosf(e);
    __syncthreads();
    float a1 = b1[c];
    for (int kk = 0; kk < TD; kk++) a1 += emb[kk] * W1[kk * H + c];
    z[c] = silu_f(a1);
    __syncthreads();
    float a2 = b2[c];
    for (int kk = 0; kk < H; kk++) a2 += z[kk] * W2[kk * H + c];
    t_emb[g * H + c] = a2;
}

// ---------------------------------------------------------------------------
// CSR build
// ---------------------------------------------------------------------------
__global__ __launch_bounds__(256) void hist_dst(const int* __restrict__ edge_index,
                                                int* __restrict__ deg)
{
    int e = blockIdx.x * 256 + threadIdx.x;
    if (e < N_EDGES) atomicAdd(&deg[edge_index[N_EDGES + e]], 1);
}

// batch is sorted: gptr[g] = lower_bound(batch, g)
__global__ __launch_bounds__(320) void gptr_bsearch(const int* __restrict__ batch,
                                                    int* __restrict__ gptr)
{
    int g = threadIdx.x;
    if (g > NB) return;
    int lo = 0, hi = N_NODES;
    while (lo < hi) {
        int mid = (lo + hi) >> 1;
        if (batch[mid] < g) lo = mid + 1; else hi = mid;
    }
    gptr[g] = lo;
}

__global__ __launch_bounds__(256) void scan_part(const int* __restrict__ cnt,
                                                 int* __restrict__ bsum, int n)
{
    int tid = threadIdx.x;
    int i0 = blockIdx.x * 1024 + tid * 4;
    int s = 0;
#pragma unroll
    for (int j = 0; j < 4; j++) if (i0 + j < n) s += cnt[i0 + j];
    __shared__ int red[256];
    red[tid] = s;
    __syncthreads();
    for (int off = 128; off >= 1; off >>= 1) {
        if (tid < off) red[tid] += red[tid + off];
        __syncthreads();
    }
    if (tid == 0) bsum[blockIdx.x] = red[0];
}

__global__ __launch_bounds__(256) void scan_tops(const int* __restrict__ bsum,
                                                 int* __restrict__ boff, int G,
                                                 int* __restrict__ total)
{
    int tid = threadIdx.x;
    int v = (tid < G) ? bsum[tid] : 0;
    __shared__ int ps[256];
    ps[tid] = v;
    __syncthreads();
    for (int off = 1; off < 256; off <<= 1) {
        int t = (tid >= off) ? ps[tid - off] : 0;
        __syncthreads();
        ps[tid] += t;
        __syncthreads();
    }
    if (tid < G) boff[tid] = ps[tid] - v;
    if (tid == 255) *total = ps[255];
}

__global__ __launch_bounds__(256) void scan_final(const int* __restrict__ cnt,
                                                  const int* __restrict__ boff,
                                                  int* __restrict__ ptr, int n)
{
    int tid = threadIdx.x;
    int i0 = blockIdx.x * 1024 + tid * 4;
    int v[4];
#pragma unroll
    for (int j = 0; j < 4; j++) v[j] = (i0 + j < n) ? cnt[i0 + j] : 0;
    int s = v[0] + v[1] + v[2] + v[3];
    __shared__ int ps[256];
    ps[tid] = s;
    __syncthreads();
    for (int off = 1; off < 256; off <<= 1) {
        int t = (tid >= off) ? ps[tid - off] : 0;
        __syncthreads();
        ps[tid] += t;
        __syncthreads();
    }
    int run = boff[blockIdx.x] + ps[tid] - s;
#pragma unroll
    for (int j = 0; j < 4; j++) {
        if (i0 + j < n) { ptr[i0 + j] = run; run += v[j]; }
    }
}

__global__ __launch_bounds__(256) void scatter_edges(const int* __restrict__ edge_index,
                                                     const int* __restrict__ ptr,
                                                     int* __restrict__ cursor,
                                                     int* __restrict__ src_csr,
                                                     int* __restrict__ rank)
{
    int e = blockIdx.x * 256 + threadIdx.x;
    if (e >= N_EDGES) return;
    int s = edge_index[e];
    int d = edge_index[N_EDGES + e];
    int pos = atomicAdd(&cursor[d], 1);
    int p = ptr[d] + pos;
    src_csr[p] = s;
    rank[e] = p;
}

// ---------------------------------------------------------------------------
// Per-edge scores, ALL 4 heads, written in CSR order as half4 via rank[e].
// ---------------------------------------------------------------------------
__global__ __launch_bounds__(256) void edge_scores_4h(
    const float* __restrict__ edge_attr, const int* __restrict__ edge_index,
    const int* __restrict__ rank, const float* __restrict__ mc_l,
    const float* __restrict__ sS, const float* __restrict__ sD,
    __half* __restrict__ alpha)
{
    __shared__ float Ml[BD * 4], cl[4];
    int tid = threadIdx.x;
    if (tid < 40) Ml[tid] = mc_l[tid];
    if (tid >= 40 && tid < 44) cl[tid - 40] = mc_l[tid];
    __syncthreads();
    int e = blockIdx.x * 256 + tid;
    if (e >= N_EDGES) return;
    float se0 = cl[0], se1 = cl[1], se2 = cl[2], se3 = cl[3];
#pragma unroll
    for (int j = 0; j < BD; j++) {
        float x = edge_attr[(size_t)e * BD + j];
        se0 += x * Ml[j * 4 + 0]; se1 += x * Ml[j * 4 + 1];
        se2 += x * Ml[j * 4 + 2]; se3 += x * Ml[j * 4 + 3];
    }
    int s = edge_index[e];
    int d = edge_index[N_EDGES + e];
    float4 ss = *(const float4*)&sS[s * 4];
    float4 sd = *(const float4*)&sD[d * 4];
    float a0 = ss.x + sd.x + se0; a0 = (a0 >= 0.f) ? a0 : 0.2f * a0;
    float a1 = ss.y + sd.y + se1; a1 = (a1 >= 0.f) ? a1 : 0.2f * a1;
    float a2 = ss.z + sd.z + se2; a2 = (a2 >= 0.f) ? a2 : 0.2f * a2;
    float a3 = ss.w + sd.w + se3; a3 = (a3 >= 0.f) ? a3 : 0.2f * a3;
    __half2 h01 = __floats2half2_rn(a0, a1);
    __half2 h23 = __floats2half2_rn(a2, a3);
    uint2 u = make_uint2(*(const unsigned*)&h01, *(const unsigned*)&h23);
    int p = rank[e];
    *(uint2*)&alpha[(size_t)p * 4] = u;
}

// ---------------------------------------------------------------------------
// GAT aggregation for one half: one wave per dst node, online softmax.
// ---------------------------------------------------------------------------
__global__ __launch_bounds__(256) void gat_agg_h(
    const float* __restrict__ xh, int coff, const __half* __restrict__ alpha,
    int hh0, const int* __restrict__ csr_ptr, const int* __restrict__ src_csr,
    const float* __restrict__ conv_b_off, float* __restrict__ agg)
{
    int n = (blockIdx.x * 256 + threadIdx.x) >> 6;
    if (n >= N_NODES) return;
    int lane = threadIdx.x & 63;
    int c = coff + lane;
    int hoff = hh0 + (lane >> 5);
    int start = csr_ptr[n], end = csr_ptr[n + 1];

    float m_run = -1e30f, d_run = 0.f, acc = 0.f;

    for (int base = start; base < end; base += 64) {
        int cnt = min(64, end - base);
        int s_l = (lane < cnt) ? src_csr[base + lane] : 0;
        int i0 = lane & 31;
        float a0 = (i0 < cnt)      ? __half2float(alpha[(size_t)(base + i0) * 4 + hoff])      : -1e30f;
        float a1 = (i0 + 32 < cnt) ? __half2float(alpha[(size_t)(base + i0 + 32) * 4 + hoff]) : -1e30f;

        float m_blk = fmaxf(a0, a1);
#pragma unroll
        for (int off = 16; off >= 1; off >>= 1)
            m_blk = fmaxf(m_blk, __shfl_xor(m_blk, off, 32));
        float m_new = fmaxf(m_run, m_blk);
        float rescale = __expf(m_run - m_new);
        float e0 = __expf(a0 - m_new);
        float e1 = __expf(a1 - m_new);
        float dsum = e0 + e1;
#pragma unroll
        for (int off = 16; off >= 1; off >>= 1)
            dsum += __shfl_xor(dsum, off, 32);
        d_run = d_run * rescale + dsum;
        acc *= rescale;

        int c1 = min(cnt, 32);
        for (int i = 0; i < c1; i += 4) {
            int s0 = __shfl(s_l, i + 0), s1 = __shfl(s_l, i + 1);
            int s2 = __shfl(s_l, i + 2), s3 = __shfl(s_l, i + 3);
            float w0 = __shfl(e0, i + 0, 32), w1 = __shfl(e0, i + 1, 32);
            float w2 = __shfl(e0, i + 2, 32), w3 = __shfl(e0, i + 3, 32);
            float x0 = xh[(size_t)s0 * H + c];
            float x1 = xh[(size_t)s1 * H + c];
            float x2 = xh[(size_t)s2 * H + c];
            float x3 = xh[(size_t)s3 * H + c];
            acc += x0 * w0 + x1 * w1 + x2 * w2 + x3 * w3;
        }
        for (int i = 32; i < cnt; i += 4) {
            int s0 = __shfl(s_l, i + 0), s1 = __shfl(s_l, i + 1);
            int s2 = __shfl(s_l, i + 2), s3 = __shfl(s_l, i + 3);
            float w0 = __shfl(e1, i - 32, 32), w1 = __shfl(e1, i - 31, 32);
            float w2 = __shfl(e1, i - 30, 32), w3 = __shfl(e1, i - 29, 32);
            float x0 = xh[(size_t)s0 * H + c];
            float x1 = xh[(size_t)s1 * H + c];
            float x2 = xh[(size_t)s2 * H + c];
            float x3 = xh[(size_t)s3 * H + c];
            acc += x0 * w0 + x1 * w1 + x2 * w2 + x3 * w3;
        }
        m_run = m_new;
    }
    float inv = 1.f / (d_run + 1e-16f);
    agg[(size_t)n * HQ + lane] = acc * inv + conv_b_off[lane];
}

// ---------------------------------------------------------------------------
// BatchNorm (per half, 64 channels)
// ---------------------------------------------------------------------------
__global__ __launch_bounds__(256) void bn_partial_h(const float* __restrict__ agg,
                                                    float* __restrict__ part)
{
    __shared__ float red[2][4][64];
    int b = blockIdx.x;
    int c = threadIdx.x & 63;
    int q = threadIdx.x >> 6;
    int per = (N_NODES + 255) / 256;
    int s = b * per, e = min(N_NODES, s + per);
    int qs = s + q * ((per + 3) / 4);
    int qe = min(e, qs + (per + 3) / 4);
    float sum = 0.f, sq = 0.f;
    for (int n = qs; n < qe; n++) {
        float v = agg[(size_t)n * HQ + c];
        sum += v; sq += v * v;
    }
    red[0][q][c] = sum;
    red[1][q][c] = sq;
    __syncthreads();
    if (q == 0) {
        sum = red[0][0][c] + red[0][1][c] + red[0][2][c] + red[0][3][c];
        sq  = red[1][0][c] + red[1][1][c] + red[1][2][c] + red[1][3][c];
        part[b * HQ + c] = sum;
        part[256 * HQ + b * HQ + c] = sq;
    }
}

__global__ __launch_bounds__(256) void bn_finish_h(const float* __restrict__ part,
                                                   const float* __restrict__ gamma,
                                                   const float* __restrict__ beta,
                                                   float* __restrict__ scale,
                                                   float* __restrict__ shift)
{
    __shared__ double red[2][4][64];
    int c = threadIdx.x & 63;
    int g = threadIdx.x >> 6;
    double s = 0.0, q = 0.0;
    for (int b = g * 64; b < (g + 1) * 64; b++) {
        s += (double)part[b * HQ + c];
        q += (double)part[256 * HQ + b * HQ + c];
    }
    red[0][g][c] = s;
    red[1][g][c] = q;
    __syncthreads();
    if (g == 0) {
        s = red[0][0][c] + red[0][1][c] + red[0][2][c] + red[0][3][c];
        q = red[1][0][c] + red[1][1][c] + red[1][2][c] + red[1][3][c];
        float mu = (float)(s / N_NODES);
        float var = (float)(q / N_NODES) - mu * mu;
        float rstd = rsqrtf(var + 1e-5f);
        float sc = gamma[c] * rstd;
        scale[c] = sc;
        shift[c] = beta[c] - mu * sc;
    }
}

__global__ __launch_bounds__(256) void bn_apply_h(const float* __restrict__ agg,
                                                  const float* __restrict__ scale,
                                                  const float* __restrict__ shift,
                                                  float* __restrict__ h, int coff)
{
    int i = blockIdx.x * 256 + threadIdx.x;
    if (i >= N_NODES * HQ / 4) return;
    int n = i >> 4;
    int c0 = (i & 15) * 4;
    float4 v = *(const float4*)&agg[(size_t)n * HQ + c0];
    float4 sc = *(const float4*)&scale[c0];
    float4 sh = *(const float4*)&shift[c0];
    float* hp = &h[(size_t)n * H + coff + c0];
    float4 hv = *(const float4*)hp;
    float4 o;
    o.x = fmaxf(v.x * sc.x + sh.x, 0.f) + hv.x;
    o.y = fmaxf(v.y * sc.y + sh.y, 0.f) + hv.y;
    o.z = fmaxf(v.z * sc.z + sh.z, 0.f) + hv.z;
    o.w = fmaxf(v.w * sc.w + sh.w, 0.f) + hv.w;
    *(float4*)hp = o;
}

// ---------------------------------------------------------------------------
// Graph pooling, stage 1: per-(graph, quarter) partial sums of node features.
// grid = NB*4 blocks x 128 threads.
// ---------------------------------------------------------------------------
__global__ __launch_bounds__(128) void pool_partial(
    const float* __restrict__ nf, const int* __restrict__ gptr,
    float* __restrict__ pprt)
{
    int g = blockIdx.x >> 2;
    int q = blockIdx.x & 3;
    int c = threadIdx.x;
    int s = gptr[g], e = gptr[g + 1];
    int qlen = (e - s + 3) >> 2;
    int qs = s + q * qlen;
    int qe = min(e, qs + qlen);
    float sum = 0.f;
    for (int n = qs; n < qe; n++) sum += nf[(size_t)n * H + c];
    pprt[((size_t)g * 4 + q) * H + c] = sum;
}

// ---------------------------------------------------------------------------
// Graph head MLP: one 512-thread block per graph; q = K-quarter, c = channel.
// tgW[g][c] = npb1[c] + sum_k tg[k]*npW1[128+k][c],
// tg = t_emb + pool_b2 + silu(mean @ pW1 + pb1) @ pW2.
// ---------------------------------------------------------------------------
__global__ __launch_bounds__(512) void graph_head_mlp(
    const int* __restrict__ gptr, const float* __restrict__ pprt,
    const float* __restrict__ t_emb,
    const float* __restrict__ pW1, const float* __restrict__ pb1,
    const float* __restrict__ pW2, const float* __restrict__ pb2,
    const float* __restrict__ npW1, const float* __restrict__ npb1,
    float* __restrict__ tgW)
{
    int g = blockIdx.x;
    int c = threadIdx.x & 127;
    int q = threadIdx.x >> 7;
    __shared__ float row[H], z[H];
    __shared__ float red[4][H];

    int s = gptr[g], e = gptr[g + 1];
    float cf = (e - s > 0) ? (float)(e - s) : 1.f;
    if (q == 0) {
        row[c] = (pprt[((size_t)g * 4 + 0) * H + c] +
                  pprt[((size_t)g * 4 + 1) * H + c] +
                  pprt[((size_t)g * 4 + 2) * H + c] +
                  pprt[((size_t)g * 4 + 3) * H + c]) / cf;
    }
    __syncthreads();

    float p = 0.f;
#pragma unroll 8
    for (int k = q * 32; k < q * 32 + 32; k++) p += row[k] * pW1[k * H + c];
    red[q][c] = p;
    __syncthreads();
    if (q == 0) z[c] = silu_f(red[0][c] + red[1][c] + red[2][c] + red[3][c] + pb1[c]);
    __syncthreads();

    p = 0.f;
#pragma unroll 8
    for (int k = q * 32; k < q * 32 + 32; k++) p += z[k] * pW2[k * H + c];
    red[q][c] = p;
    __syncthreads();
    if (q == 0) row[c] = red[0][c] + red[1][c] + red[2][c] + red[3][c] + pb2[c]
                         + t_emb[g * H + c];
    __syncthreads();

    p = 0.f;
#pragma unroll 8
    for (int k = q * 32; k < q * 32 + 32; k++)
        p += row[k] * npW1[(size_t)(128 + k) * H + c];
    red[q][c] = p;
    __syncthreads();
    if (q == 0) tgW[g * H + c] = red[0][c] + red[1][c] + red[2][c] + red[3][c] + npb1[c];
}

// ---------------------------------------------------------------------------
extern "C" void kernel_launch(void* const* d_in, const int* in_sizes, int n_in,
                              void* d_out, int out_size, void* d_ws, size_t ws_size,
                              hipStream_t stream)
{
    const float* x          = (const float*)d_in[0];
    const int*   edge_index = (const int*)d_in[1];
    const float* edge_attr  = (const float*)d_in[2];
    const int*   batch      = (const int*)d_in[3];
    const int*   t          = (const int*)d_in[4];
    const float* atom_W     = (const float*)d_in[5];
    const float* atom_b     = (const float*)d_in[6];
    const float* bond_W     = (const float*)d_in[7];
    const float* bond_b     = (const float*)d_in[8];
    const float* lin_W      = (const float*)d_in[9];
    const float* edge_W     = (const float*)d_in[10];
    const float* att_src    = (const float*)d_in[11];
    const float* att_dst    = (const float*)d_in[12];
    const float* att_edge   = (const float*)d_in[13];
    const float* conv_b     = (const float*)d_in[14];
    const float* bn_gamma   = (const float*)d_in[15];
    const float* bn_beta    = (const float*)d_in[16];
    const float* out_W      = (const float*)d_in[17];
    const float* out_b      = (const float*)d_in[18];
    const float* time_W1    = (const float*)d_in[19];
    const float* time_b1    = (const float*)d_in[20];
    const float* time_W2    = (const float*)d_in[21];
    const float* time_b2    = (const float*)d_in[22];
    const float* pool_W1    = (const float*)d_in[23];
    const float* pool_b1    = (const float*)d_in[24];
    const float* pool_W2    = (const float*)d_in[25];
    const float* pool_b2    = (const float*)d_in[26];
    const float* np_W1      = (const float*)d_in[27];
    const float* np_b1      = (const float*)d_in[28];
    const float* np_W2      = (const float*)d_in[29];
    const float* np_b2      = (const float*)d_in[30];
    const float* np_W3      = (const float*)d_in[31];
    const float* np_b3      = (const float*)d_in[32];

    // ---------------- workspace layout (floats), total 71.6 MB ----------------
    const size_t OFF_H     = 0;                      // [N*H]
    const size_t OFF_XH    = 6400000;                // [N*H]
    const size_t OFF_AGG   = 12800000;               // [N*HQ] (also pool partials)
    const size_t OFF_ALPHA = 16000000;               // half[E][4] = 1.6M floats
    const size_t OFF_SD    = 17600000;               // [N*4]
    const size_t OFF_TEMB  = 17800000;               // [NB*H]
    const size_t OFF_TGW   = 17832768;               // [NB*H]
    const size_t OFF_MC    = 17865536;               // 256
    const size_t OFF_BNSC  = 17865792;               // 128
    const size_t OFF_BNSH  = 17865920;               // 128
    const size_t OFF_PART  = 17866048;               // 32768
    const size_t REQ_FLOATS = 17898816;
    const size_t REQ_BYTES  = REQ_FLOATS * 4;        // 71,595,264 (proven OK)

    if (ws_size < REQ_BYTES) {
        hipMemsetAsync(d_out, 0, (size_t)out_size * sizeof(float), stream);
        return;
    }

    float* fws    = (float*)d_ws;
    float* h      = fws + OFF_H;
    float* xh     = fws + OFF_XH;
    float* agg    = fws + OFF_AGG;
    __half* alpha = (__half*)(fws + OFF_ALPHA);
    float* sD     = fws + OFF_SD;
    float* t_emb  = fws + OFF_TEMB;
    float* tgW    = fws + OFF_TGW;
    float* mc     = fws + OFF_MC;
    float* bnsc   = fws + OFF_BNSC;
    float* bnsh   = fws + OFF_BNSH;
    float* part   = fws + OFF_PART;
    float* pprt   = agg;   // pool partials [NB*4*H] = 131072 floats (agg is dead)

    // d_out scratch (1,950,000 floats): CSR ints + rank + sS.
    int* ib       = (int*)d_out;
    int* csr_ptr  = ib;                    // 50,016
    int* src_csr  = ib + 50016;            // 800,000
    int* rank     = ib + 850016;           // 800,000
    int* deg      = ib + 1650016;          // 50,016 (hist + scatter cursor)
    int* gptr     = ib + 1700032;          // 260
    int* bsum     = ib + 1700292;          // 64
    int* boff     = ib + 1700356;          // 64
    float* sS     = (float*)d_out + 1700420;  // [N*4] (end 1,900,420)

    hipMemsetAsync(deg, 0, N_NODES * sizeof(int), stream);

    precompute_small<<<1, 256, 0, stream>>>(edge_W, att_edge, bond_W, bond_b, mc);
    time_embed<<<NB, 128, 0, stream>>>(t, time_W1, time_b1, time_W2, time_b2, t_emb);
    gptr_bsearch<<<1, 320, 0, stream>>>(batch, gptr);

    hist_dst<<<(N_EDGES + 255) / 256, 256, 0, stream>>>(edge_index, deg);

    const int GSN = (N_NODES + 1023) / 1024;  // 49
    scan_part<<<GSN, 256, 0, stream>>>(deg, bsum, N_NODES);
    scan_tops<<<1, 256, 0, stream>>>(bsum, boff, GSN, &csr_ptr[N_NODES]);
    scan_final<<<GSN, 256, 0, stream>>>(deg, boff, csr_ptr, N_NODES);

    hipMemsetAsync(deg, 0, N_NODES * sizeof(int), stream);
    scatter_edges<<<(N_EDGES + 255) / 256, 256, 0, stream>>>(edge_index, csr_ptr,
                                                             deg, src_csr, rank);

    const int GB = (N_NODES + 63) / 64;

    // h = x @ atom_W + atom_b
    gemm128<AD><<<GB, 256, 0, stream>>>(x, atom_W, atom_b, nullptr, nullptr,
                                        h, N_NODES, H, 0,
                                        nullptr, nullptr, nullptr, nullptr);

    for (int l = 0; l < LAYERS; l++) {
        // xh = h @ lin_W[l], fused attention scores sS/sD
        gemm128<H><<<GB, 256, 0, stream>>>(h, lin_W + (size_t)l * H * H, nullptr,
                                           nullptr, nullptr, xh, N_NODES, H, 0,
                                           att_src + l * H, att_dst + l * H, sS, sD);
        edge_scores_4h<<<(N_EDGES + 255) / 256, 256, 0, stream>>>(
            edge_attr, edge_index, rank, mc + l * 44, sS, sD, alpha);
        for (int half = 0; half < 2; half++) {
            int hh0 = half * 2;
            int coff = half * HQ;
            gat_agg_h<<<N_NODES / 4, 256, 0, stream>>>(
                xh, coff, alpha, hh0, csr_ptr, src_csr, conv_b + l * H + coff, agg);
            bn_partial_h<<<256, 256, 0, stream>>>(agg, part);
            bn_finish_h<<<1, 256, 0, stream>>>(part, bn_gamma + l * H + coff,
                                               bn_beta + l * H + coff, bnsc, bnsh);
            bn_apply_h<<<(N_NODES * HQ / 4 + 255) / 256, 256, 0, stream>>>(
                agg, bnsc, bnsh, h, coff);
        }
    }

    // node_features = h @ out_W + out_b  -> xh
    gemm128<H><<<GB, 256, 0, stream>>>(h, out_W, out_b, nullptr, nullptr,
                                       xh, N_NODES, H, 0,
                                       nullptr, nullptr, nullptr, nullptr);

    // graph pooling + head MLP (agg reused as pool partials; dead after loop)
    pool_partial<<<NB * 4, 128, 0, stream>>>(xh, gptr, pprt);
    graph_head_mlp<<<NB, 512, 0, stream>>>(gptr, pprt, t_emb, pool_W1, pool_b1,
                                           pool_W2, pool_b2, np_W1, np_b1, tgW);

    // z1 = silu(nf @ np_W1[0:128] + tgW[batch]) -> h
    gemm128<H><<<GB, 256, 0, stream>>>(xh, np_W1, nullptr, tgW, batch,
                                       h, N_NODES, H, 1,
                                       nullptr, nullptr, nullptr, nullptr);
    // z2 = silu(z1 @ np_W2 + np_b2) -> xh
    gemm128<H><<<GB, 256, 0, stream>>>(h, np_W2, np_b2, nullptr, nullptr,
                                       xh, N_NODES, H, 1,
                                       nullptr, nullptr, nullptr, nullptr);
    // out = z2 @ np_W3 + np_b3 -> d_out [N,39]
    gemm_out39<<<(N_NODES + 99) / 100, 256, 0, stream>>>(xh, np_W3, np_b3,
                                                         (float*)d_out, N_NODES);
}